// Round 16
// baseline (399.910 us; speedup 1.0000x reference)
//
#include <hip/hip_runtime.h>
#include <hip/hip_bf16.h>
#include <math.h>

#define HIDDEN   1024
#define HEADS    16
#define HEAD_DIM 64
#define BATCH    4
#define SEQ      4096
#define M_TOTAL  (BATCH * SEQ)          // 16384
#define FFT_N    4096
#define WSZ      ((size_t)HIDDEN * HIDDEN)
#define PI2      6.28318530717958647692f

typedef _Float16 f16x8 __attribute__((ext_vector_type(8)));   // 8 fp16 = 4 VGPR (MFMA A/B frag)
typedef float    f32x4 __attribute__((ext_vector_type(4)));   // MFMA C/D frag

#if defined(__has_builtin)
#if __has_builtin(__builtin_amdgcn_global_load_lds)
#define HAVE_GLL 1
#else
#define HAVE_GLL 0
#endif
#else
#define HAVE_GLL 0
#endif

#if HAVE_GLL
// async global->LDS, 16B/lane. dest = wave-uniform base + lane*16 (linear in slot).
__device__ __forceinline__ void gload16(const void* g, void* l) {
    __builtin_amdgcn_global_load_lds(
        (const __attribute__((address_space(1))) unsigned int*)g,
        (__attribute__((address_space(3))) unsigned int*)l,
        16, 0, 0);
}
#endif

// fp16 one-sided split: v = hi + lo + O(2^-22 |v|)   (r11/r12/r15-validated math)
__device__ __forceinline__ void split8_f16(float4 v0, float4 v1,
                                           ushort* __restrict__ hd,
                                           ushort* __restrict__ ld) {
    const float vv[8] = {v0.x, v0.y, v0.z, v0.w, v1.x, v1.y, v1.z, v1.w};
    f16x8 hv, lv;
    #pragma unroll
    for (int e = 0; e < 8; ++e) {
        const _Float16 h = (_Float16)vv[e];
        hv[e] = h;
        lv[e] = (_Float16)(vv[e] - (float)h);
    }
    *(f16x8*)hd = hv;
    *(f16x8*)ld = lv;
}

__device__ __forceinline__ void cvt8_f16(float4 v0, float4 v1,
                                         ushort* __restrict__ d) {
    const float vv[8] = {v0.x, v0.y, v0.z, v0.w, v1.x, v1.y, v1.z, v1.w};
    f16x8 hv;
    #pragma unroll
    for (int e = 0; e < 8; ++e) hv[e] = (_Float16)vv[e];
    *(f16x8*)d = hv;
}

__device__ __forceinline__ void split1_f16(float v, ushort& h, ushort& l) {
    const _Float16 hh = (_Float16)v;
    const _Float16 ll = (_Float16)(v - (float)hh);
    union { _Float16 f; ushort u; } ch, cl;
    ch.f = hh; cl.f = ll;
    h = ch.u; l = cl.u;
}

// ---------------------------------------------------------------------------
// Pre-pass kernels (validated r12/r15)
// ---------------------------------------------------------------------------
__global__ __launch_bounds__(256) void split16_kernel(
    const float* __restrict__ src, ushort* __restrict__ h,
    ushort* __restrict__ l)
{
    const size_t i = ((size_t)blockIdx.x * 256 + threadIdx.x) * 8;
    float4 v0 = *(const float4*)(src + i);
    float4 v1 = *(const float4*)(src + i + 4);
    split8_f16(v0, v1, h + i, l + i);
}

__global__ __launch_bounds__(256) void cvt16_kernel(
    const float* __restrict__ src, ushort* __restrict__ h)
{
    const size_t i = ((size_t)blockIdx.x * 256 + threadIdx.x) * 8;
    float4 v0 = *(const float4*)(src + i);
    float4 v1 = *(const float4*)(src + i + 4);
    cvt8_f16(v0, v1, h + i);
}

// ---------------------------------------------------------------------------
// QKV GEMM (MFMA fp16, gload16 staging, triple-buffer + counted vmcnt):
// r15-VALIDATED structure (180 us, MfmaUtil 53.7%). This round's delta:
//  (1) T5 setprio(1) around the MFMA cluster (counted-vmcnt gives the wave
//      role-split that makes setprio pay; r8's null was lockstep 2-phase);
//  (2) issue-early STAGE: STAGE(ks+2) moved to right after the barrier,
//      before compute -- loads gain a full compute phase of flight time.
// vmcnt algebra unchanged: at iter-t wait, outstanding = STAGE(t+1) (3)
// -> vmcnt(3) certifies tile t. STAGE(t+2) writes slot (t-1)%3 whose
// readers finished before barrier t. Math byte-identical to r15.
// ---------------------------------------------------------------------------
__global__ __launch_bounds__(1024, 1) void gemm_qkv_mfma7(
    const ushort* __restrict__ xh,
    const ushort* __restrict__ wh, const ushort* __restrict__ wl,
    const float* __restrict__ bq, const float* __restrict__ bk,
    const float* __restrict__ bv,
    float* __restrict__ qkvt)
{
    __shared__ ushort Ah[3][8192], Al[3][8192];   // W tile [256n][32k] hi/lo fp16
    __shared__ ushort Bh[3][8192];                // x tile [256m][32k] fp16 (144 KiB)

    const int tid  = threadIdx.x;
    const int lane = tid & 63;
    const int wid  = tid >> 6;
    const int wr   = wid >> 2;        // n-dim wave 0..3
    const int wc   = wid & 3;         // m-dim wave 0..3
    const int m0   = blockIdx.x * 256;
    const int ng0  = blockIdx.y * 256;            // stacked n in [0,3072)
    const int p    = ng0 >> 10;
    const int n0p  = ng0 & 1023;

    const float* __restrict__ bias = (p == 0) ? bq : (p == 1 ? bk : bv);
    float* __restrict__ ct = qkvt + (size_t)p * HIDDEN * M_TOTAL;

    const int row = tid >> 2;         // [0,256)
    const int chS = (tid & 3) ^ ((row >> 1) & 3);   // inverse-swizzled source chunk

    const int fr = lane & 15;
    const int fc = lane >> 4;
    const int cc = (fc ^ ((fr >> 1) & 3)) * 8;

    f32x4 acc[4][4];
    #pragma unroll
    for (int rf = 0; rf < 4; ++rf)
        #pragma unroll
        for (int cf = 0; cf < 4; ++cf)
            acc[rf][cf] = (f32x4){0.f, 0.f, 0.f, 0.f};

#if HAVE_GLL
    #define QKV_STAGE(K0, SLOT) {                                                  \
        const size_t gw = (size_t)(ng0 + row) * HIDDEN + (K0) + (size_t)chS * 8;   \
        const size_t gx = (size_t)(m0 + row) * HIDDEN + (K0) + (size_t)chS * 8;    \
        gload16(wh + gw, &Ah[SLOT][(size_t)tid * 8]);                              \
        gload16(wl + gw, &Al[SLOT][(size_t)tid * 8]);                              \
        gload16(xh + gx, &Bh[SLOT][(size_t)tid * 8]);                              \
    }
#else
    #define QKV_STAGE(K0, SLOT) {                                                  \
        const size_t gw = (size_t)(ng0 + row) * HIDDEN + (K0) + (size_t)chS * 8;   \
        const size_t gx = (size_t)(m0 + row) * HIDDEN + (K0) + (size_t)chS * 8;    \
        *(f16x8*)&Ah[SLOT][(size_t)tid * 8] = *(const f16x8*)(wh + gw);            \
        *(f16x8*)&Al[SLOT][(size_t)tid * 8] = *(const f16x8*)(wl + gw);            \
        *(f16x8*)&Bh[SLOT][(size_t)tid * 8] = *(const f16x8*)(xh + gx);            \
    }
#endif

    QKV_STAGE(0, 0);
    QKV_STAGE(32, 1);

    for (int ks = 0; ks < 32; ++ks) {
        const int slot = ks % 3;
#if HAVE_GLL
        if (ks == 31) { asm volatile("s_waitcnt vmcnt(0)" ::: "memory"); }
        else          { asm volatile("s_waitcnt vmcnt(3)" ::: "memory"); }
        __builtin_amdgcn_s_barrier();
        asm volatile("" ::: "memory");      // fence: keep ds_reads below barrier
        if (ks + 2 < 32) { QKV_STAGE((ks + 2) * 32, (ks + 2) % 3); }   // issue-early
#else
        __syncthreads();
        if (ks + 2 < 32) { QKV_STAGE((ks + 2) * 32, (ks + 2) % 3); }
#endif
        {   // compute(ks): 32 MFMA / wave, product-major (r11/r12/r15-validated)
            const ushort* pAh = Ah[slot];
            const ushort* pAl = Al[slot];
            const ushort* pBh = Bh[slot];
            f16x8 a_h[4], a_l[4], b_h[4];
            #pragma unroll
            for (int rf = 0; rf < 4; ++rf) {
                const int R = wr * 64 + rf * 16 + fr;
                a_h[rf] = *(const f16x8*)(pAh + R * 32 + cc);
                a_l[rf] = *(const f16x8*)(pAl + R * 32 + cc);
            }
            #pragma unroll
            for (int cf = 0; cf < 4; ++cf) {
                const int R = wc * 64 + cf * 16 + fr;
                b_h[cf] = *(const f16x8*)(pBh + R * 32 + cc);
            }
            __builtin_amdgcn_s_setprio(1);
            #pragma unroll
            for (int rf = 0; rf < 4; ++rf)
                #pragma unroll
                for (int cf = 0; cf < 4; ++cf)
                    acc[rf][cf] = __builtin_amdgcn_mfma_f32_16x16x32_f16(a_h[rf], b_h[cf], acc[rf][cf], 0, 0, 0);
            #pragma unroll
            for (int rf = 0; rf < 4; ++rf)
                #pragma unroll
                for (int cf = 0; cf < 4; ++cf)
                    acc[rf][cf] = __builtin_amdgcn_mfma_f32_16x16x32_f16(a_l[rf], b_h[cf], acc[rf][cf], 0, 0, 0);
            __builtin_amdgcn_s_setprio(0);
        }
#if !HAVE_GLL
        __syncthreads();
#endif
    }
    #undef QKV_STAGE

    // epilogue (validated r7-r15): row n_local = wr*64+rf*16+rq*4+r ; col m = wc*64+cf*16+fr
    const int rq = lane >> 4;
    #pragma unroll
    for (int rf = 0; rf < 4; ++rf) {
        #pragma unroll
        for (int r = 0; r < 4; ++r) {
            const int nl = wr * 64 + rf * 16 + rq * 4 + r;
            const float bv = bias[n0p + nl];
            float* dst = ct + (size_t)(n0p + nl) * M_TOTAL + m0 + wc * 64;
            #pragma unroll
            for (int cf = 0; cf < 4; ++cf)
                dst[cf * 16 + fr] = acc[rf][cf][r] + bv;
        }
    }
}

// ---------------------------------------------------------------------------
// Radix-16 FFT machinery (UNCHANGED, validated r5-r15 full-batch form)
// ---------------------------------------------------------------------------
__device__ __forceinline__ float2 cmul(float2 a, float2 b) {
    return {a.x*b.x - a.y*b.y, a.x*b.y + a.y*b.x};
}

__device__ __forceinline__ int phys(int p) { return p ^ ((p >> 4) & 15); }

template<int DIR>
__device__ __forceinline__ void dft16(const float2* x, float2* X) {
    float2 t[16];
    #pragma unroll
    for (int n0 = 0; n0 < 4; ++n0) {
        float2 a = x[n0], b = x[n0+4], c = x[n0+8], d = x[n0+12];
        float2 s0 = {a.x+c.x, a.y+c.y}, s1 = {a.x-c.x, a.y-c.y};
        float2 s2 = {b.x+d.x, b.y+d.y}, s3 = {b.x-d.x, b.y-d.y};
        t[n0*4+0] = {s0.x+s2.x, s0.y+s2.y};
        t[n0*4+2] = {s0.x-s2.x, s0.y-s2.y};
        if (DIR < 0) {
            t[n0*4+1] = {s1.x+s3.y, s1.y-s3.x};
            t[n0*4+3] = {s1.x-s3.y, s1.y+s3.x};
        } else {
            t[n0*4+1] = {s1.x-s3.y, s1.y+s3.x};
            t[n0*4+3] = {s1.x+s3.y, s1.y-s3.x};
        }
    }
    const float C1 = 0.92387953251128674f;
    const float S1_ = 0.38268343236508978f;
    const float R2 = 0.70710678118654752f;
    #define TW(idx, cc_, ss_) t[idx] = cmul(t[idx], (float2){cc_, DIR*(ss_)})
    TW(1*4+1, C1, S1_);   TW(1*4+2, R2, R2);    TW(1*4+3, S1_, C1);
    TW(2*4+1, R2, R2);    TW(2*4+2, 0.f, 1.f);  TW(2*4+3, -R2, R2);
    TW(3*4+1, S1_, C1);   TW(3*4+2, -R2, R2);   TW(3*4+3, -C1, -S1_);
    #undef TW
    #pragma unroll
    for (int k0 = 0; k0 < 4; ++k0) {
        float2 a = t[0+k0], b = t[4+k0], c = t[8+k0], d = t[12+k0];
        float2 s0 = {a.x+c.x, a.y+c.y}, s1 = {a.x-c.x, a.y-c.y};
        float2 s2 = {b.x+d.x, b.y+d.y}, s3 = {b.x-d.x, b.y-d.y};
        X[k0+0]  = {s0.x+s2.x, s0.y+s2.y};
        X[k0+8]  = {s0.x-s2.x, s0.y-s2.y};
        if (DIR < 0) {
            X[k0+4]  = {s1.x+s3.y, s1.y-s3.x};
            X[k0+12] = {s1.x-s3.y, s1.y+s3.x};
        } else {
            X[k0+4]  = {s1.x-s3.y, s1.y+s3.x};
            X[k0+12] = {s1.x+s3.y, s1.y-s3.x};
        }
    }
}

__device__ __forceinline__ void twiddle_apply(float2* y, float ang) {
    float s, c;
    __sincosf(ang, &s, &c);
    const float2 base = {c, s};
    float2 w = base;
    #pragma unroll
    for (int u = 1; u < 16; ++u) {
        y[u] = cmul(y[u], w);
        w = cmul(w, base);
    }
}

__global__ __launch_bounds__(256) void fft_attn_kernel(
    const float* __restrict__ qt, const float* __restrict__ kt,
    const float* __restrict__ vt, float* __restrict__ ot)
{
    __shared__ float2 bufA[FFT_N];
    __shared__ float2 bufB[FFT_N];

    const int tid = threadIdx.x;
    const int bid = blockIdx.x;
    const int n   = bid >> 2;
    const int b   = bid & 3;

    const size_t off = (size_t)n * M_TOTAL + (size_t)b * SEQ;
    const float* qrow = qt + off;
    const float* krow = kt + off;
    const float* vrow = vt + off;
    float*       orow = ot + off;

    {
        const int q = tid;
        float2 xA[16], xB[16], yA[16], yB[16];
        #pragma unroll
        for (int r = 0; r < 16; ++r) {
            xA[r] = { qrow[q + 256*r], krow[q + 256*r] };
            xB[r] = { vrow[q + 256*r], 0.f };
        }
        dft16<-1>(xA, yA);
        dft16<-1>(xB, yB);
        const float ang = -PI2 * (float)q / 4096.f;
        twiddle_apply(yA, ang);
        twiddle_apply(yB, ang);
        #pragma unroll
        for (int u = 0; u < 16; ++u) {
            bufA[phys(q + 256*u)] = yA[u];
            bufB[phys(q + 256*u)] = yB[u];
        }
    }
    __syncthreads();
    {
        const int blk = tid >> 4, a = tid & 15;
        const int base = 256*blk + a;
        float2 xA[16], xB[16], yA[16], yB[16];
        #pragma unroll
        for (int c = 0; c < 16; ++c) {
            xA[c] = bufA[phys(base + 16*c)];
            xB[c] = bufB[phys(base + 16*c)];
        }
        dft16<-1>(xA, yA);
        dft16<-1>(xB, yB);
        const float ang = -PI2 * (float)a / 256.f;
        twiddle_apply(yA, ang);
        twiddle_apply(yB, ang);
        #pragma unroll
        for (int c = 0; c < 16; ++c) {
            bufA[phys(base + 16*c)] = yA[c];
            bufB[phys(base + 16*c)] = yB[c];
        }
    }
    __syncthreads();
    {
        const int blk = tid >> 4, c = tid & 15;
        const int base = 256*blk + 16*c;
        float2 xA[16], xB[16], yA[16], yB[16];
        #pragma unroll
        for (int a2 = 0; a2 < 16; ++a2) {
            xA[a2] = bufA[phys(base + a2)];
            xB[a2] = bufB[phys(base + a2)];
        }
        dft16<-1>(xA, yA);
        dft16<-1>(xB, yB);
        #pragma unroll
        for (int d = 0; d < 16; ++d) {
            bufA[phys(base + d)] = yA[d];
            bufB[phys(base + d)] = yB[d];
        }
    }
    __syncthreads();
    #pragma unroll
    for (int it = 0; it < 16; ++it) {
        const int p  = tid + it * 256;
        const int j  = ((p & 15) << 8) | (p & 0xF0) | (p >> 8);
        const int jn = (FFT_N - j) & (FFT_N - 1);
        const int pn = ((jn & 15) << 8) | (jn & 0xF0) | (jn >> 8);
        const float2 Zj = bufA[phys(p)];
        const float2 Zn = bufA[phys(pn)];
        const float2 Q = { 0.5f*(Zj.x + Zn.x), 0.5f*(Zj.y - Zn.y) };
        const float2 K = { 0.5f*(Zj.y + Zn.y), -0.5f*(Zj.x - Zn.x) };
        const float2 G = { Q.x*K.x + Q.y*K.y, Q.y*K.x - Q.x*K.y };
        const float2 V = bufB[phys(p)];
        bufB[phys(p)] = { G.x*V.x - G.y*V.y, G.x*V.y + G.y*V.x };
    }
    __syncthreads();
    {
        const int blk = tid >> 4, c = tid & 15;
        const int base = 256*blk + 16*c;
        float2 x[16], y[16];
        #pragma unroll
        for (int d = 0; d < 16; ++d) x[d] = bufB[phys(base + d)];
        dft16<1>(x, y);
        #pragma unroll
        for (int p0 = 0; p0 < 16; ++p0) bufB[phys(base + p0)] = y[p0];
    }
    __syncthreads();
    {
        const int blk = tid >> 4, p0 = tid & 15;
        const int base = 256*blk + p0;
        float2 x[16], y[16];
        #pragma unroll
        for (int c = 0; c < 16; ++c) x[c] = bufB[phys(base + 16*c)];
        twiddle_apply(x, PI2 * (float)p0 / 256.f);
        dft16<1>(x, y);
        #pragma unroll
        for (int p1 = 0; p1 < 16; ++p1) bufB[phys(base + 16*p1)] = y[p1];
    }
    __syncthreads();
    {
        const int qq = tid;
        float2 x[16], y[16];
        #pragma unroll
        for (int t = 0; t < 16; ++t) x[t] = bufB[phys(qq + 256*t)];
        twiddle_apply(x, PI2 * (float)qq / 4096.f);
        dft16<1>(x, y);
        const float scale = 0.125f / 4096.f;
        #pragma unroll
        for (int p2 = 0; p2 < 16; ++p2)
            orow[qq + 256*p2] = y[p2].x * scale;
    }
}

// ---------------------------------------------------------------------------
// Transpose + fp16 split (UNCHANGED, validated r11-r15)
// ---------------------------------------------------------------------------
__global__ __launch_bounds__(256) void transpose_split_kernel(
    const float* __restrict__ ot, ushort* __restrict__ oth,
    ushort* __restrict__ otl)
{
    __shared__ float tile[64][65];
    const int tid = threadIdx.x;
    const int m0  = blockIdx.x * 64;
    const int n0  = blockIdx.y * 64;
    const int r   = tid >> 4;
    const int c   = tid & 15;

    #pragma unroll
    for (int rr = 0; rr < 4; ++rr) {
        const int nl = r + rr * 16;
        float4 v = *(const float4*)(ot + (size_t)(n0 + nl) * M_TOTAL + m0 + c * 4);
        tile[nl][c * 4 + 0] = v.x; tile[nl][c * 4 + 1] = v.y;
        tile[nl][c * 4 + 2] = v.z; tile[nl][c * 4 + 3] = v.w;
    }
    __syncthreads();
    #pragma unroll
    for (int rr = 0; rr < 4; ++rr) {
        const int ml = r + rr * 16;
        ushort4 hh, ll;
        split1_f16(tile[c * 4 + 0][ml], hh.x, ll.x);
        split1_f16(tile[c * 4 + 1][ml], hh.y, ll.y);
        split1_f16(tile[c * 4 + 2][ml], hh.z, ll.z);
        split1_f16(tile[c * 4 + 3][ml], hh.w, ll.w);
        *(ushort4*)(oth + (size_t)(m0 + ml) * HIDDEN + n0 + c * 4) = hh;
        *(ushort4*)(otl + (size_t)(m0 + ml) * HIDDEN + n0 + c * 4) = ll;
    }
}

// ---------------------------------------------------------------------------
// Output GEMM (MFMA fp16, gload16 staging, triple-buffer + counted vmcnt)
// Same r15-validated structure + this round's setprio / issue-early deltas.
// ---------------------------------------------------------------------------
__global__ __launch_bounds__(1024, 1) void gemm_out_mfma7(
    const ushort* __restrict__ oth, const ushort* __restrict__ otl,
    const ushort* __restrict__ woh, const float* __restrict__ bo,
    float* __restrict__ out)
{
    __shared__ ushort Ah[3][8192], Al[3][8192];   // ot^T tile [256m][32k] hi/lo
    __shared__ ushort Bh[3][8192];                // Wo tile [256n][32k] fp16

    const int tid  = threadIdx.x;
    const int lane = tid & 63;
    const int wid  = tid >> 6;
    const int wr   = wid >> 2;        // m-dim wave
    const int wc   = wid & 3;         // n-dim wave
    const int m0   = blockIdx.x * 256;
    const int n0   = blockIdx.y * 256;

    const int row = tid >> 2;
    const int chS = (tid & 3) ^ ((row >> 1) & 3);

    const int fr = lane & 15;
    const int fc = lane >> 4;
    const int cc = (fc ^ ((fr >> 1) & 3)) * 8;

    f32x4 acc[4][4];
    #pragma unroll
    for (int rf = 0; rf < 4; ++rf)
        #pragma unroll
        for (int cf = 0; cf < 4; ++cf)
            acc[rf][cf] = (f32x4){0.f, 0.f, 0.f, 0.f};

#if HAVE_GLL
    #define OUT_STAGE(K0, SLOT) {                                                  \
        const size_t ga = (size_t)(m0 + row) * HIDDEN + (K0) + (size_t)chS * 8;    \
        const size_t gb = (size_t)(n0 + row) * HIDDEN + (K0) + (size_t)chS * 8;    \
        gload16(oth + ga, &Ah[SLOT][(size_t)tid * 8]);                             \
        gload16(otl + ga, &Al[SLOT][(size_t)tid * 8]);                             \
        gload16(woh + gb, &Bh[SLOT][(size_t)tid * 8]);                             \
    }
#else
    #define OUT_STAGE(K0, SLOT) {                                                  \
        const size_t ga = (size_t)(m0 + row) * HIDDEN + (K0) + (size_t)chS * 8;    \
        const size_t gb = (size_t)(n0 + row) * HIDDEN + (K0) + (size_t)chS * 8;    \
        *(f16x8*)&Ah[SLOT][(size_t)tid * 8] = *(const f16x8*)(oth + ga);           \
        *(f16x8*)&Al[SLOT][(size_t)tid * 8] = *(const f16x8*)(otl + ga);           \
        *(f16x8*)&Bh[SLOT][(size_t)tid * 8] = *(const f16x8*)(woh + gb);           \
    }
#endif

    OUT_STAGE(0, 0);
    OUT_STAGE(32, 1);

    for (int ks = 0; ks < 32; ++ks) {
        const int slot = ks % 3;
#if HAVE_GLL
        if (ks == 31) { asm volatile("s_waitcnt vmcnt(0)" ::: "memory"); }
        else          { asm volatile("s_waitcnt vmcnt(3)" ::: "memory"); }
        __builtin_amdgcn_s_barrier();
        asm volatile("" ::: "memory");
        if (ks + 2 < 32) { OUT_STAGE((ks + 2) * 32, (ks + 2) % 3); }   // issue-early
#else
        __syncthreads();
        if (ks + 2 < 32) { OUT_STAGE((ks + 2) * 32, (ks + 2) % 3); }
#endif
        {
            const ushort* pAh = Ah[slot];
            const ushort* pAl = Al[slot];
            const ushort* pBh = Bh[slot];
            f16x8 a_h[4], a_l[4], b_h[4];
            #pragma unroll
            for (int rf = 0; rf < 4; ++rf) {
                const int R = wr * 64 + rf * 16 + fr;
                a_h[rf] = *(const f16x8*)(pAh + R * 32 + cc);
                a_l[rf] = *(const f16x8*)(pAl + R * 32 + cc);
            }
            #pragma unroll
            for (int cf = 0; cf < 4; ++cf) {
                const int R = wc * 64 + cf * 16 + fr;
                b_h[cf] = *(const f16x8*)(pBh + R * 32 + cc);
            }
            __builtin_amdgcn_s_setprio(1);
            #pragma unroll
            for (int rf = 0; rf < 4; ++rf)
                #pragma unroll
                for (int cf = 0; cf < 4; ++cf)
                    acc[rf][cf] = __builtin_amdgcn_mfma_f32_16x16x32_f16(a_h[rf], b_h[cf], acc[rf][cf], 0, 0, 0);
            #pragma unroll
            for (int rf = 0; rf < 4; ++rf)
                #pragma unroll
                for (int cf = 0; cf < 4; ++cf)
                    acc[rf][cf] = __builtin_amdgcn_mfma_f32_16x16x32_f16(a_l[rf], b_h[cf], acc[rf][cf], 0, 0, 0);
            __builtin_amdgcn_s_setprio(0);
        }
#if !HAVE_GLL
        __syncthreads();
#endif
    }
    #undef OUT_STAGE

    // epilogue: D row m_local = wr*64+rf*16+rq*4+r ; col n_local = wc*64+cf*16+fr
    const int rq = lane >> 4;
    float bo_v[4];
    #pragma unroll
    for (int cf = 0; cf < 4; ++cf) bo_v[cf] = bo[n0 + wc * 64 + cf * 16 + fr];
    #pragma unroll
    for (int rf = 0; rf < 4; ++rf) {
        #pragma unroll
        for (int r = 0; r < 4; ++r) {
            const int ml = wr * 64 + rf * 16 + rq * 4 + r;
            float* dst = out + (size_t)(m0 + ml) * HIDDEN + n0 + wc * 64;
            #pragma unroll
            for (int cf = 0; cf < 4; ++cf)
                dst[cf * 16 + fr] = acc[rf][cf][r] + bo_v[cf];
        }
    }
}

// ---------------------------------------------------------------------------
// Buffers (ws = proven 201.3 MB; fp16 operand planes stashed in d_out):
//   ws:    qt/kt/vt fp32 full planes (67.1 MB each).
//   d_out: xh fp16 @0 (33.55 MB), wh @33.55 (6.29), wl @39.84 (6.29) --
//          dead once qkv completes; gemm_out then overwrites d_out.
//   After fft: kt plane -> oth+otl; vt plane -> woh. ot aliases qt.
// ---------------------------------------------------------------------------
extern "C" void kernel_launch(void* const* d_in, const int* in_sizes, int n_in,
                              void* d_out, int out_size, void* d_ws, size_t ws_size,
                              hipStream_t stream)
{
    const float* x  = (const float*)d_in[0];
    const float* Wq = (const float*)d_in[1];
    const float* bq = (const float*)d_in[2];
    const float* Wk = (const float*)d_in[3];
    const float* bk = (const float*)d_in[4];
    const float* Wv = (const float*)d_in[5];
    const float* bv = (const float*)d_in[6];
    const float* Wo = (const float*)d_in[7];
    const float* bo = (const float*)d_in[8];
    float* out = (float*)d_out;

    const size_t plane = (size_t)HIDDEN * M_TOTAL;   // 16.78M elements
    float* qt = (float*)d_ws;
    float* kt = qt + plane;
    float* vt = kt + plane;
    float* ot = qt;                     // FFT output aliases q plane

    // fp16 operand stash in d_out (dead until gemm_out overwrites it)
    ushort* xh = (ushort*)d_out;                    // [16384][1024]
    ushort* wh = xh + plane;                        // stacked [3072][1024]
    ushort* wl = wh + 3 * WSZ;

    // post-fft stash in dead ws planes
    ushort* oth = (ushort*)kt;                      // [16384][1024] fp16 hi
    ushort* otl = oth + plane;                      // lo (ends exactly at vt)
    ushort* woh = (ushort*)vt;                      // [1024][1024] fp16

    // pre-passes: x -> fp16; Wq/Wk/Wv -> fp16 hi/lo (into d_out stash)
    cvt16_kernel<<<(unsigned)(plane / 2048), 256, 0, stream>>>(x, xh);
    split16_kernel<<<(unsigned)(WSZ / 2048), 256, 0, stream>>>(Wq, wh, wl);
    split16_kernel<<<(unsigned)(WSZ / 2048), 256, 0, stream>>>(Wk, wh + WSZ, wl + WSZ);
    split16_kernel<<<(unsigned)(WSZ / 2048), 256, 0, stream>>>(Wv, wh + 2 * WSZ, wl + 2 * WSZ);

    // QKV projections (full batch, 768 blocks = 3x256)
    gemm_qkv_mfma7<<<dim3(M_TOTAL / 256, 12), 1024, 0, stream>>>(
        xh, wh, wl, bq, bk, bv, qt);

    // FFT attention (full batch, writes ot = qt in place)
    fft_attn_kernel<<<dim3(HIDDEN * BATCH), 256, 0, stream>>>(qt, kt, vt, ot);

    // Wo -> fp16 into dead vt plane
    cvt16_kernel<<<(unsigned)(WSZ / 2048), 256, 0, stream>>>(Wo, woh);

    // transpose ot -> fp16 hi/lo [m][k] into dead kt plane
    transpose_split_kernel<<<dim3(M_TOTAL / 64, HIDDEN / 64), 256, 0, stream>>>(
        ot, oth, otl);

    // output projection (256 blocks, overwrites d_out)
    gemm_out_mfma7<<<dim3(M_TOTAL / 256, HIDDEN / 256), 1024, 0, stream>>>(
        oth, otl, woh, bo, out);
}

// Round 17
// 388.851 us; speedup vs baseline: 1.0284x; 1.0284x over previous
//
#include <hip/hip_runtime.h>
#include <hip/hip_bf16.h>
#include <math.h>

#define HIDDEN   1024
#define HEADS    16
#define HEAD_DIM 64
#define BATCH    4
#define SEQ      4096
#define M_TOTAL  (BATCH * SEQ)          // 16384
#define FFT_N    4096
#define WSZ      ((size_t)HIDDEN * HIDDEN)
#define PI2      6.28318530717958647692f

typedef _Float16 f16x8 __attribute__((ext_vector_type(8)));   // 8 fp16 = 4 VGPR (MFMA A/B frag)
typedef float    f32x4 __attribute__((ext_vector_type(4)));   // MFMA C/D frag

#if defined(__has_builtin)
#if __has_builtin(__builtin_amdgcn_global_load_lds)
#define HAVE_GLL 1
#else
#define HAVE_GLL 0
#endif
#else
#define HAVE_GLL 0
#endif

#if HAVE_GLL
// async global->LDS, 16B/lane. dest = wave-uniform base + lane*16 (linear in slot).
__device__ __forceinline__ void gload16(const void* g, void* l) {
    __builtin_amdgcn_global_load_lds(
        (const __attribute__((address_space(1))) unsigned int*)g,
        (__attribute__((address_space(3))) unsigned int*)l,
        16, 0, 0);
}
#endif

// fp16 one-sided split: v = hi + lo + O(2^-22 |v|)   (r11-r15-validated math)
__device__ __forceinline__ void split8_f16(float4 v0, float4 v1,
                                           ushort* __restrict__ hd,
                                           ushort* __restrict__ ld) {
    const float vv[8] = {v0.x, v0.y, v0.z, v0.w, v1.x, v1.y, v1.z, v1.w};
    f16x8 hv, lv;
    #pragma unroll
    for (int e = 0; e < 8; ++e) {
        const _Float16 h = (_Float16)vv[e];
        hv[e] = h;
        lv[e] = (_Float16)(vv[e] - (float)h);
    }
    *(f16x8*)hd = hv;
    *(f16x8*)ld = lv;
}

__device__ __forceinline__ void cvt8_f16(float4 v0, float4 v1,
                                         ushort* __restrict__ d) {
    const float vv[8] = {v0.x, v0.y, v0.z, v0.w, v1.x, v1.y, v1.z, v1.w};
    f16x8 hv;
    #pragma unroll
    for (int e = 0; e < 8; ++e) hv[e] = (_Float16)vv[e];
    *(f16x8*)d = hv;
}

__device__ __forceinline__ void split1_f16(float v, ushort& h, ushort& l) {
    const _Float16 hh = (_Float16)v;
    const _Float16 ll = (_Float16)(v - (float)hh);
    union { _Float16 f; ushort u; } ch, cl;
    ch.f = hh; cl.f = ll;
    h = ch.u; l = cl.u;
}

// ---------------------------------------------------------------------------
// Pre-pass kernels. cvt16 (r12/r15-validated); W-split merged: one launch
// handles Wq/Wk/Wv via blockIdx.y (same math as 3x split16, fewer launches).
// ---------------------------------------------------------------------------
__global__ __launch_bounds__(256) void cvt16_kernel(
    const float* __restrict__ src, ushort* __restrict__ h)
{
    const size_t i = ((size_t)blockIdx.x * 256 + threadIdx.x) * 8;
    float4 v0 = *(const float4*)(src + i);
    float4 v1 = *(const float4*)(src + i + 4);
    cvt8_f16(v0, v1, h + i);
}

__global__ __launch_bounds__(256) void splitW_kernel(
    const float* __restrict__ Wq, const float* __restrict__ Wk,
    const float* __restrict__ Wv,
    ushort* __restrict__ h, ushort* __restrict__ l)
{
    const int p = blockIdx.y;                 // 0=q 1=k 2=v
    const float* __restrict__ src = (p == 0) ? Wq : (p == 1 ? Wk : Wv);
    const size_t i = ((size_t)blockIdx.x * 256 + threadIdx.x) * 8;
    const size_t o = (size_t)p * WSZ + i;
    float4 v0 = *(const float4*)(src + i);
    float4 v1 = *(const float4*)(src + i + 4);
    split8_f16(v0, v1, h + o, l + o);
}

// ---------------------------------------------------------------------------
// QKV GEMM (MFMA fp16, gload16 staging, TRIPLE-buffer + counted vmcnt):
// r15-VALIDATED structure, byte-identical K-loop (180 us, MfmaUtil 53.7%).
// r16's setprio + issue-early REVERTED: both hurt (199 us, MfmaUtil 47%) --
// T5 is null-to-negative in lockstep barrier loops (m190; confirmed r8+r16).
// T4 schedule: per iter {wait vmcnt(3) -> raw s_barrier -> compute(ks) ->
// STAGE(ks+2)}. Loads never drained to 0 in the main loop.
// ---------------------------------------------------------------------------
__global__ __launch_bounds__(1024, 1) void gemm_qkv_mfma7(
    const ushort* __restrict__ xh,
    const ushort* __restrict__ wh, const ushort* __restrict__ wl,
    const float* __restrict__ bq, const float* __restrict__ bk,
    const float* __restrict__ bv,
    float* __restrict__ qkvt)
{
    __shared__ ushort Ah[3][8192], Al[3][8192];   // W tile [256n][32k] hi/lo fp16
    __shared__ ushort Bh[3][8192];                // x tile [256m][32k] fp16 (144 KiB)

    const int tid  = threadIdx.x;
    const int lane = tid & 63;
    const int wid  = tid >> 6;
    const int wr   = wid >> 2;        // n-dim wave 0..3
    const int wc   = wid & 3;         // m-dim wave 0..3
    const int m0   = blockIdx.x * 256;
    const int ng0  = blockIdx.y * 256;            // stacked n in [0,3072)
    const int p    = ng0 >> 10;
    const int n0p  = ng0 & 1023;

    const float* __restrict__ bias = (p == 0) ? bq : (p == 1 ? bk : bv);
    float* __restrict__ ct = qkvt + (size_t)p * HIDDEN * M_TOTAL;

    const int row = tid >> 2;         // [0,256)
    const int chS = (tid & 3) ^ ((row >> 1) & 3);   // inverse-swizzled source chunk

    const int fr = lane & 15;
    const int fc = lane >> 4;
    const int cc = (fc ^ ((fr >> 1) & 3)) * 8;

    f32x4 acc[4][4];
    #pragma unroll
    for (int rf = 0; rf < 4; ++rf)
        #pragma unroll
        for (int cf = 0; cf < 4; ++cf)
            acc[rf][cf] = (f32x4){0.f, 0.f, 0.f, 0.f};

#if HAVE_GLL
    #define QKV_STAGE(K0, SLOT) {                                                  \
        const size_t gw = (size_t)(ng0 + row) * HIDDEN + (K0) + (size_t)chS * 8;   \
        const size_t gx = (size_t)(m0 + row) * HIDDEN + (K0) + (size_t)chS * 8;    \
        gload16(wh + gw, &Ah[SLOT][(size_t)tid * 8]);                              \
        gload16(wl + gw, &Al[SLOT][(size_t)tid * 8]);                              \
        gload16(xh + gx, &Bh[SLOT][(size_t)tid * 8]);                              \
    }
#else
    #define QKV_STAGE(K0, SLOT) {                                                  \
        const size_t gw = (size_t)(ng0 + row) * HIDDEN + (K0) + (size_t)chS * 8;   \
        const size_t gx = (size_t)(m0 + row) * HIDDEN + (K0) + (size_t)chS * 8;    \
        *(f16x8*)&Ah[SLOT][(size_t)tid * 8] = *(const f16x8*)(wh + gw);            \
        *(f16x8*)&Al[SLOT][(size_t)tid * 8] = *(const f16x8*)(wl + gw);            \
        *(f16x8*)&Bh[SLOT][(size_t)tid * 8] = *(const f16x8*)(xh + gx);            \
    }
#endif

    QKV_STAGE(0, 0);
    QKV_STAGE(32, 1);

    for (int ks = 0; ks < 32; ++ks) {
        const int slot = ks % 3;
#if HAVE_GLL
        if (ks == 31) { asm volatile("s_waitcnt vmcnt(0)" ::: "memory"); }
        else          { asm volatile("s_waitcnt vmcnt(3)" ::: "memory"); }
        __builtin_amdgcn_s_barrier();
        asm volatile("" ::: "memory");      // fence: keep ds_reads below barrier
#else
        __syncthreads();
#endif
        {   // compute(ks): 32 MFMA / wave, product-major (r11-r15-validated)
            const ushort* pAh = Ah[slot];
            const ushort* pAl = Al[slot];
            const ushort* pBh = Bh[slot];
            f16x8 a_h[4], a_l[4], b_h[4];
            #pragma unroll
            for (int rf = 0; rf < 4; ++rf) {
                const int R = wr * 64 + rf * 16 + fr;
                a_h[rf] = *(const f16x8*)(pAh + R * 32 + cc);
                a_l[rf] = *(const f16x8*)(pAl + R * 32 + cc);
            }
            #pragma unroll
            for (int cf = 0; cf < 4; ++cf) {
                const int R = wc * 64 + cf * 16 + fr;
                b_h[cf] = *(const f16x8*)(pBh + R * 32 + cc);
            }
            #pragma unroll
            for (int rf = 0; rf < 4; ++rf)
                #pragma unroll
                for (int cf = 0; cf < 4; ++cf)
                    acc[rf][cf] = __builtin_amdgcn_mfma_f32_16x16x32_f16(a_h[rf], b_h[cf], acc[rf][cf], 0, 0, 0);
            #pragma unroll
            for (int rf = 0; rf < 4; ++rf)
                #pragma unroll
                for (int cf = 0; cf < 4; ++cf)
                    acc[rf][cf] = __builtin_amdgcn_mfma_f32_16x16x32_f16(a_l[rf], b_h[cf], acc[rf][cf], 0, 0, 0);
        }
        if (ks + 2 < 32) { QKV_STAGE((ks + 2) * 32, (ks + 2) % 3); }
#if !HAVE_GLL
        __syncthreads();
#endif
    }
    #undef QKV_STAGE

    // epilogue (validated r7-r15): row n_local = wr*64+rf*16+rq*4+r ; col m = wc*64+cf*16+fr
    const int rq = lane >> 4;
    #pragma unroll
    for (int rf = 0; rf < 4; ++rf) {
        #pragma unroll
        for (int r = 0; r < 4; ++r) {
            const int nl = wr * 64 + rf * 16 + rq * 4 + r;
            const float bv = bias[n0p + nl];
            float* dst = ct + (size_t)(n0p + nl) * M_TOTAL + m0 + wc * 64;
            #pragma unroll
            for (int cf = 0; cf < 4; ++cf)
                dst[cf * 16 + fr] = acc[rf][cf][r] + bv;
        }
    }
}

// ---------------------------------------------------------------------------
// Radix-16 FFT machinery (UNCHANGED, validated r5-r15 full-batch form)
// ---------------------------------------------------------------------------
__device__ __forceinline__ float2 cmul(float2 a, float2 b) {
    return {a.x*b.x - a.y*b.y, a.x*b.y + a.y*b.x};
}

__device__ __forceinline__ int phys(int p) { return p ^ ((p >> 4) & 15); }

template<int DIR>
__device__ __forceinline__ void dft16(const float2* x, float2* X) {
    float2 t[16];
    #pragma unroll
    for (int n0 = 0; n0 < 4; ++n0) {
        float2 a = x[n0], b = x[n0+4], c = x[n0+8], d = x[n0+12];
        float2 s0 = {a.x+c.x, a.y+c.y}, s1 = {a.x-c.x, a.y-c.y};
        float2 s2 = {b.x+d.x, b.y+d.y}, s3 = {b.x-d.x, b.y-d.y};
        t[n0*4+0] = {s0.x+s2.x, s0.y+s2.y};
        t[n0*4+2] = {s0.x-s2.x, s0.y-s2.y};
        if (DIR < 0) {
            t[n0*4+1] = {s1.x+s3.y, s1.y-s3.x};
            t[n0*4+3] = {s1.x-s3.y, s1.y+s3.x};
        } else {
            t[n0*4+1] = {s1.x-s3.y, s1.y+s3.x};
            t[n0*4+3] = {s1.x+s3.y, s1.y-s3.x};
        }
    }
    const float C1 = 0.92387953251128674f;
    const float S1_ = 0.38268343236508978f;
    const float R2 = 0.70710678118654752f;
    #define TW(idx, cc_, ss_) t[idx] = cmul(t[idx], (float2){cc_, DIR*(ss_)})
    TW(1*4+1, C1, S1_);   TW(1*4+2, R2, R2);    TW(1*4+3, S1_, C1);
    TW(2*4+1, R2, R2);    TW(2*4+2, 0.f, 1.f);  TW(2*4+3, -R2, R2);
    TW(3*4+1, S1_, C1);   TW(3*4+2, -R2, R2);   TW(3*4+3, -C1, -S1_);
    #undef TW
    #pragma unroll
    for (int k0 = 0; k0 < 4; ++k0) {
        float2 a = t[0+k0], b = t[4+k0], c = t[8+k0], d = t[12+k0];
        float2 s0 = {a.x+c.x, a.y+c.y}, s1 = {a.x-c.x, a.y-c.y};
        float2 s2 = {b.x+d.x, b.y+d.y}, s3 = {b.x-d.x, b.y-d.y};
        X[k0+0]  = {s0.x+s2.x, s0.y+s2.y};
        X[k0+8]  = {s0.x-s2.x, s0.y-s2.y};
        if (DIR < 0) {
            X[k0+4]  = {s1.x+s3.y, s1.y-s3.x};
            X[k0+12] = {s1.x-s3.y, s1.y+s3.x};
        } else {
            X[k0+4]  = {s1.x-s3.y, s1.y+s3.x};
            X[k0+12] = {s1.x+s3.y, s1.y-s3.x};
        }
    }
}

__device__ __forceinline__ void twiddle_apply(float2* y, float ang) {
    float s, c;
    __sincosf(ang, &s, &c);
    const float2 base = {c, s};
    float2 w = base;
    #pragma unroll
    for (int u = 1; u < 16; ++u) {
        y[u] = cmul(y[u], w);
        w = cmul(w, base);
    }
}

__global__ __launch_bounds__(256) void fft_attn_kernel(
    const float* __restrict__ qt, const float* __restrict__ kt,
    const float* __restrict__ vt, float* __restrict__ ot)
{
    __shared__ float2 bufA[FFT_N];
    __shared__ float2 bufB[FFT_N];

    const int tid = threadIdx.x;
    const int bid = blockIdx.x;
    const int n   = bid >> 2;
    const int b   = bid & 3;

    const size_t off = (size_t)n * M_TOTAL + (size_t)b * SEQ;
    const float* qrow = qt + off;
    const float* krow = kt + off;
    const float* vrow = vt + off;
    float*       orow = ot + off;

    {
        const int q = tid;
        float2 xA[16], xB[16], yA[16], yB[16];
        #pragma unroll
        for (int r = 0; r < 16; ++r) {
            xA[r] = { qrow[q + 256*r], krow[q + 256*r] };
            xB[r] = { vrow[q + 256*r], 0.f };
        }
        dft16<-1>(xA, yA);
        dft16<-1>(xB, yB);
        const float ang = -PI2 * (float)q / 4096.f;
        twiddle_apply(yA, ang);
        twiddle_apply(yB, ang);
        #pragma unroll
        for (int u = 0; u < 16; ++u) {
            bufA[phys(q + 256*u)] = yA[u];
            bufB[phys(q + 256*u)] = yB[u];
        }
    }
    __syncthreads();
    {
        const int blk = tid >> 4, a = tid & 15;
        const int base = 256*blk + a;
        float2 xA[16], xB[16], yA[16], yB[16];
        #pragma unroll
        for (int c = 0; c < 16; ++c) {
            xA[c] = bufA[phys(base + 16*c)];
            xB[c] = bufB[phys(base + 16*c)];
        }
        dft16<-1>(xA, yA);
        dft16<-1>(xB, yB);
        const float ang = -PI2 * (float)a / 256.f;
        twiddle_apply(yA, ang);
        twiddle_apply(yB, ang);
        #pragma unroll
        for (int c = 0; c < 16; ++c) {
            bufA[phys(base + 16*c)] = yA[c];
            bufB[phys(base + 16*c)] = yB[c];
        }
    }
    __syncthreads();
    {
        const int blk = tid >> 4, c = tid & 15;
        const int base = 256*blk + 16*c;
        float2 xA[16], xB[16], yA[16], yB[16];
        #pragma unroll
        for (int a2 = 0; a2 < 16; ++a2) {
            xA[a2] = bufA[phys(base + a2)];
            xB[a2] = bufB[phys(base + a2)];
        }
        dft16<-1>(xA, yA);
        dft16<-1>(xB, yB);
        #pragma unroll
        for (int d = 0; d < 16; ++d) {
            bufA[phys(base + d)] = yA[d];
            bufB[phys(base + d)] = yB[d];
        }
    }
    __syncthreads();
    #pragma unroll
    for (int it = 0; it < 16; ++it) {
        const int p  = tid + it * 256;
        const int j  = ((p & 15) << 8) | (p & 0xF0) | (p >> 8);
        const int jn = (FFT_N - j) & (FFT_N - 1);
        const int pn = ((jn & 15) << 8) | (jn & 0xF0) | (jn >> 8);
        const float2 Zj = bufA[phys(p)];
        const float2 Zn = bufA[phys(pn)];
        const float2 Q = { 0.5f*(Zj.x + Zn.x), 0.5f*(Zj.y - Zn.y) };
        const float2 K = { 0.5f*(Zj.y + Zn.y), -0.5f*(Zj.x - Zn.x) };
        const float2 G = { Q.x*K.x + Q.y*K.y, Q.y*K.x - Q.x*K.y };
        const float2 V = bufB[phys(p)];
        bufB[phys(p)] = { G.x*V.x - G.y*V.y, G.x*V.y + G.y*V.x };
    }
    __syncthreads();
    {
        const int blk = tid >> 4, c = tid & 15;
        const int base = 256*blk + 16*c;
        float2 x[16], y[16];
        #pragma unroll
        for (int d = 0; d < 16; ++d) x[d] = bufB[phys(base + d)];
        dft16<1>(x, y);
        #pragma unroll
        for (int p0 = 0; p0 < 16; ++p0) bufB[phys(base + p0)] = y[p0];
    }
    __syncthreads();
    {
        const int blk = tid >> 4, p0 = tid & 15;
        const int base = 256*blk + p0;
        float2 x[16], y[16];
        #pragma unroll
        for (int c = 0; c < 16; ++c) x[c] = bufB[phys(base + 16*c)];
        twiddle_apply(x, PI2 * (float)p0 / 256.f);
        dft16<1>(x, y);
        #pragma unroll
        for (int p1 = 0; p1 < 16; ++p1) bufB[phys(base + 16*p1)] = y[p1];
    }
    __syncthreads();
    {
        const int qq = tid;
        float2 x[16], y[16];
        #pragma unroll
        for (int t = 0; t < 16; ++t) x[t] = bufB[phys(qq + 256*t)];
        twiddle_apply(x, PI2 * (float)qq / 4096.f);
        dft16<1>(x, y);
        const float scale = 0.125f / 4096.f;
        #pragma unroll
        for (int p2 = 0; p2 < 16; ++p2)
            orow[qq + 256*p2] = y[p2].x * scale;
    }
}

// ---------------------------------------------------------------------------
// Transpose + fp16 split (UNCHANGED, validated r11-r15)
// ---------------------------------------------------------------------------
__global__ __launch_bounds__(256) void transpose_split_kernel(
    const float* __restrict__ ot, ushort* __restrict__ oth,
    ushort* __restrict__ otl)
{
    __shared__ float tile[64][65];
    const int tid = threadIdx.x;
    const int m0  = blockIdx.x * 64;
    const int n0  = blockIdx.y * 64;
    const int r   = tid >> 4;
    const int c   = tid & 15;

    #pragma unroll
    for (int rr = 0; rr < 4; ++rr) {
        const int nl = r + rr * 16;
        float4 v = *(const float4*)(ot + (size_t)(n0 + nl) * M_TOTAL + m0 + c * 4);
        tile[nl][c * 4 + 0] = v.x; tile[nl][c * 4 + 1] = v.y;
        tile[nl][c * 4 + 2] = v.z; tile[nl][c * 4 + 3] = v.w;
    }
    __syncthreads();
    #pragma unroll
    for (int rr = 0; rr < 4; ++rr) {
        const int ml = r + rr * 16;
        ushort4 hh, ll;
        split1_f16(tile[c * 4 + 0][ml], hh.x, ll.x);
        split1_f16(tile[c * 4 + 1][ml], hh.y, ll.y);
        split1_f16(tile[c * 4 + 2][ml], hh.z, ll.z);
        split1_f16(tile[c * 4 + 3][ml], hh.w, ll.w);
        *(ushort4*)(oth + (size_t)(m0 + ml) * HIDDEN + n0 + c * 4) = hh;
        *(ushort4*)(otl + (size_t)(m0 + ml) * HIDDEN + n0 + c * 4) = ll;
    }
}

// ---------------------------------------------------------------------------
// Output GEMM (MFMA fp16, gload16 staging, triple-buffer + counted vmcnt)
// r15-exact structure (setprio / issue-early reverted). 256 blocks.
// ---------------------------------------------------------------------------
__global__ __launch_bounds__(1024, 1) void gemm_out_mfma7(
    const ushort* __restrict__ oth, const ushort* __restrict__ otl,
    const ushort* __restrict__ woh, const float* __restrict__ bo,
    float* __restrict__ out)
{
    __shared__ ushort Ah[3][8192], Al[3][8192];   // ot^T tile [256m][32k] hi/lo
    __shared__ ushort Bh[3][8192];                // Wo tile [256n][32k] fp16

    const int tid  = threadIdx.x;
    const int lane = tid & 63;
    const int wid  = tid >> 6;
    const int wr   = wid >> 2;        // m-dim wave
    const int wc   = wid & 3;         // n-dim wave
    const int m0   = blockIdx.x * 256;
    const int n0   = blockIdx.y * 256;

    const int row = tid >> 2;
    const int chS = (tid & 3) ^ ((row >> 1) & 3);

    const int fr = lane & 15;
    const int fc = lane >> 4;
    const int cc = (fc ^ ((fr >> 1) & 3)) * 8;

    f32x4 acc[4][4];
    #pragma unroll
    for (int rf = 0; rf < 4; ++rf)
        #pragma unroll
        for (int cf = 0; cf < 4; ++cf)
            acc[rf][cf] = (f32x4){0.f, 0.f, 0.f, 0.f};

#if HAVE_GLL
    #define OUT_STAGE(K0, SLOT) {                                                  \
        const size_t ga = (size_t)(m0 + row) * HIDDEN + (K0) + (size_t)chS * 8;    \
        const size_t gb = (size_t)(n0 + row) * HIDDEN + (K0) + (size_t)chS * 8;    \
        gload16(oth + ga, &Ah[SLOT][(size_t)tid * 8]);                             \
        gload16(otl + ga, &Al[SLOT][(size_t)tid * 8]);                             \
        gload16(woh + gb, &Bh[SLOT][(size_t)tid * 8]);                             \
    }
#else
    #define OUT_STAGE(K0, SLOT) {                                                  \
        const size_t ga = (size_t)(m0 + row) * HIDDEN + (K0) + (size_t)chS * 8;    \
        const size_t gb = (size_t)(n0 + row) * HIDDEN + (K0) + (size_t)chS * 8;    \
        *(f16x8*)&Ah[SLOT][(size_t)tid * 8] = *(const f16x8*)(oth + ga);           \
        *(f16x8*)&Al[SLOT][(size_t)tid * 8] = *(const f16x8*)(otl + ga);           \
        *(f16x8*)&Bh[SLOT][(size_t)tid * 8] = *(const f16x8*)(woh + gb);           \
    }
#endif

    OUT_STAGE(0, 0);
    OUT_STAGE(32, 1);

    for (int ks = 0; ks < 32; ++ks) {
        const int slot = ks % 3;
#if HAVE_GLL
        if (ks == 31) { asm volatile("s_waitcnt vmcnt(0)" ::: "memory"); }
        else          { asm volatile("s_waitcnt vmcnt(3)" ::: "memory"); }
        __builtin_amdgcn_s_barrier();
        asm volatile("" ::: "memory");
#else
        __syncthreads();
#endif
        {
            const ushort* pAh = Ah[slot];
            const ushort* pAl = Al[slot];
            const ushort* pBh = Bh[slot];
            f16x8 a_h[4], a_l[4], b_h[4];
            #pragma unroll
            for (int rf = 0; rf < 4; ++rf) {
                const int R = wr * 64 + rf * 16 + fr;
                a_h[rf] = *(const f16x8*)(pAh + R * 32 + cc);
                a_l[rf] = *(const f16x8*)(pAl + R * 32 + cc);
            }
            #pragma unroll
            for (int cf = 0; cf < 4; ++cf) {
                const int R = wc * 64 + cf * 16 + fr;
                b_h[cf] = *(const f16x8*)(pBh + R * 32 + cc);
            }
            #pragma unroll
            for (int rf = 0; rf < 4; ++rf)
                #pragma unroll
                for (int cf = 0; cf < 4; ++cf)
                    acc[rf][cf] = __builtin_amdgcn_mfma_f32_16x16x32_f16(a_h[rf], b_h[cf], acc[rf][cf], 0, 0, 0);
            #pragma unroll
            for (int rf = 0; rf < 4; ++rf)
                #pragma unroll
                for (int cf = 0; cf < 4; ++cf)
                    acc[rf][cf] = __builtin_amdgcn_mfma_f32_16x16x32_f16(a_l[rf], b_h[cf], acc[rf][cf], 0, 0, 0);
        }
        if (ks + 2 < 32) { OUT_STAGE((ks + 2) * 32, (ks + 2) % 3); }
#if !HAVE_GLL
        __syncthreads();
#endif
    }
    #undef OUT_STAGE

    // epilogue: D row m_local = wr*64+rf*16+rq*4+r ; col n_local = wc*64+cf*16+fr
    const int rq = lane >> 4;
    float bo_v[4];
    #pragma unroll
    for (int cf = 0; cf < 4; ++cf) bo_v[cf] = bo[n0 + wc * 64 + cf * 16 + fr];
    #pragma unroll
    for (int rf = 0; rf < 4; ++rf) {
        #pragma unroll
        for (int r = 0; r < 4; ++r) {
            const int ml = wr * 64 + rf * 16 + rq * 4 + r;
            float* dst = out + (size_t)(m0 + ml) * HIDDEN + n0 + wc * 64;
            #pragma unroll
            for (int cf = 0; cf < 4; ++cf)
                dst[cf * 16 + fr] = acc[rf][cf][r] + bo_v[cf];
        }
    }
}

// ---------------------------------------------------------------------------
// Buffers (ws = proven 201.3 MB; fp16 operand planes stashed in d_out):
//   ws:    qt/kt/vt fp32 full planes (67.1 MB each).
//   d_out: xh fp16 @0 (33.55 MB), wh @33.55 (6.29), wl @39.84 (6.29) --
//          dead once qkv completes; gemm_out then overwrites d_out.
//   After fft: kt plane -> oth+otl; vt plane -> woh. ot aliases qt.
// ---------------------------------------------------------------------------
extern "C" void kernel_launch(void* const* d_in, const int* in_sizes, int n_in,
                              void* d_out, int out_size, void* d_ws, size_t ws_size,
                              hipStream_t stream)
{
    const float* x  = (const float*)d_in[0];
    const float* Wq = (const float*)d_in[1];
    const float* bq = (const float*)d_in[2];
    const float* Wk = (const float*)d_in[3];
    const float* bk = (const float*)d_in[4];
    const float* Wv = (const float*)d_in[5];
    const float* bv = (const float*)d_in[6];
    const float* Wo = (const float*)d_in[7];
    const float* bo = (const float*)d_in[8];
    float* out = (float*)d_out;

    const size_t plane = (size_t)HIDDEN * M_TOTAL;   // 16.78M elements
    float* qt = (float*)d_ws;
    float* kt = qt + plane;
    float* vt = kt + plane;
    float* ot = qt;                     // FFT output aliases q plane

    // fp16 operand stash in d_out (dead until gemm_out overwrites it)
    ushort* xh = (ushort*)d_out;                    // [16384][1024]
    ushort* wh = xh + plane;                        // stacked [3072][1024]
    ushort* wl = wh + 3 * WSZ;

    // post-fft stash in dead ws planes
    ushort* oth = (ushort*)kt;                      // [16384][1024] fp16 hi
    ushort* otl = oth + plane;                      // lo (ends exactly at vt)
    ushort* woh = (ushort*)vt;                      // [1024][1024] fp16

    // pre-passes: x -> fp16; Wq/Wk/Wv -> fp16 hi/lo (merged single launch)
    cvt16_kernel<<<(unsigned)(plane / 2048), 256, 0, stream>>>(x, xh);
    splitW_kernel<<<dim3((unsigned)(WSZ / 2048), 3), 256, 0, stream>>>(
        Wq, Wk, Wv, wh, wl);

    // QKV projections (full batch, 768 blocks = 3x256)
    gemm_qkv_mfma7<<<dim3(M_TOTAL / 256, 12), 1024, 0, stream>>>(
        xh, wh, wl, bq, bk, bv, qt);

    // FFT attention (full batch, writes ot = qt in place)
    fft_attn_kernel<<<dim3(HIDDEN * BATCH), 256, 0, stream>>>(qt, kt, vt, ot);

    // Wo -> fp16 into dead vt plane
    cvt16_kernel<<<(unsigned)(WSZ / 2048), 256, 0, stream>>>(Wo, woh);

    // transpose ot -> fp16 hi/lo [m][k] into dead kt plane
    transpose_split_kernel<<<dim3(M_TOTAL / 64, HIDDEN / 64), 256, 0, stream>>>(
        ot, oth, otl);

    // output projection (256 blocks, overwrites d_out)
    gemm_out_mfma7<<<dim3(M_TOTAL / 256, HIDDEN / 256), 1024, 0, stream>>>(
        oth, otl, woh, bo, out);
}

// Round 19
// 369.016 us; speedup vs baseline: 1.0837x; 1.0538x over previous
//
#include <hip/hip_runtime.h>
#include <hip/hip_bf16.h>
#include <math.h>

#define HIDDEN   1024
#define HEADS    16
#define HEAD_DIM 64
#define BATCH    4
#define SEQ      4096
#define M_TOTAL  (BATCH * SEQ)          // 16384
#define FFT_N    4096
#define WSZ      ((size_t)HIDDEN * HIDDEN)
#define PI2      6.28318530717958647692f

typedef _Float16 f16x8 __attribute__((ext_vector_type(8)));   // 8 fp16 = 4 VGPR (MFMA A/B frag)
typedef float    f32x4 __attribute__((ext_vector_type(4)));   // MFMA C/D frag

#if defined(__has_builtin)
#if __has_builtin(__builtin_amdgcn_global_load_lds)
#define HAVE_GLL 1
#else
#define HAVE_GLL 0
#endif
#else
#define HAVE_GLL 0
#endif

#if HAVE_GLL
// async global->LDS, 16B/lane. dest = wave-uniform base + lane*16 (linear in slot).
__device__ __forceinline__ void gload16(const void* g, void* l) {
    __builtin_amdgcn_global_load_lds(
        (const __attribute__((address_space(1))) unsigned int*)g,
        (__attribute__((address_space(3))) unsigned int*)l,
        16, 0, 0);
}
#endif

// fp16 one-sided split: v = hi + lo + O(2^-22 |v|)   (r11-r17-validated math)
__device__ __forceinline__ void split8_f16(float4 v0, float4 v1,
                                           ushort* __restrict__ hd,
                                           ushort* __restrict__ ld) {
    const float vv[8] = {v0.x, v0.y, v0.z, v0.w, v1.x, v1.y, v1.z, v1.w};
    f16x8 hv, lv;
    #pragma unroll
    for (int e = 0; e < 8; ++e) {
        const _Float16 h = (_Float16)vv[e];
        hv[e] = h;
        lv[e] = (_Float16)(vv[e] - (float)h);
    }
    *(f16x8*)hd = hv;
    *(f16x8*)ld = lv;
}

__device__ __forceinline__ void cvt8_f16(float4 v0, float4 v1,
                                         ushort* __restrict__ d) {
    const float vv[8] = {v0.x, v0.y, v0.z, v0.w, v1.x, v1.y, v1.z, v1.w};
    f16x8 hv;
    #pragma unroll
    for (int e = 0; e < 8; ++e) hv[e] = (_Float16)vv[e];
    *(f16x8*)d = hv;
}

__device__ __forceinline__ void split1_f16(float v, ushort& h, ushort& l) {
    const _Float16 hh = (_Float16)v;
    const _Float16 ll = (_Float16)(v - (float)hh);
    union { _Float16 f; ushort u; } ch, cl;
    ch.f = hh; cl.f = ll;
    h = ch.u; l = cl.u;
}

// ---------------------------------------------------------------------------
// Pre-pass kernels. cvt16 for x; ALL W conversions merged into one launch:
// blockIdx.y: 0..2 = split Wq/Wk/Wv -> wh/wl (d_out stash); 3 = cvt Wo ->
// woh (ws -- NOT d_out: gemm_out reads woh while writing d_out; r18's NaN).
// ---------------------------------------------------------------------------
__global__ __launch_bounds__(256) void cvt16_kernel(
    const float* __restrict__ src, ushort* __restrict__ h)
{
    const size_t i = ((size_t)blockIdx.x * 256 + threadIdx.x) * 8;
    float4 v0 = *(const float4*)(src + i);
    float4 v1 = *(const float4*)(src + i + 4);
    cvt8_f16(v0, v1, h + i);
}

__global__ __launch_bounds__(256) void splitW_kernel(
    const float* __restrict__ Wq, const float* __restrict__ Wk,
    const float* __restrict__ Wv, const float* __restrict__ Wo,
    ushort* __restrict__ h, ushort* __restrict__ l,
    ushort* __restrict__ woh)
{
    const int p = blockIdx.y;                 // 0=q 1=k 2=v 3=o
    const size_t i = ((size_t)blockIdx.x * 256 + threadIdx.x) * 8;
    if (p < 3) {
        const float* __restrict__ src = (p == 0) ? Wq : (p == 1 ? Wk : Wv);
        const size_t o = (size_t)p * WSZ + i;
        float4 v0 = *(const float4*)(src + i);
        float4 v1 = *(const float4*)(src + i + 4);
        split8_f16(v0, v1, h + o, l + o);
    } else {
        float4 v0 = *(const float4*)(Wo + i);
        float4 v1 = *(const float4*)(Wo + i + 4);
        cvt8_f16(v0, v1, woh + i);
    }
}

// ---------------------------------------------------------------------------
// QKV GEMM (MFMA fp16, gload16 staging, TRIPLE-buffer + counted vmcnt):
// r15/r17-VALIDATED K-loop, byte-identical (180 us, MfmaUtil 54%).
// Epilogue stores ct as fp16 (halves WRITE traffic; downstream fp16-limited).
// ---------------------------------------------------------------------------
__global__ __launch_bounds__(1024, 1) void gemm_qkv_mfma7(
    const ushort* __restrict__ xh,
    const ushort* __restrict__ wh, const ushort* __restrict__ wl,
    const float* __restrict__ bq, const float* __restrict__ bk,
    const float* __restrict__ bv,
    ushort* __restrict__ qkvt)
{
    __shared__ ushort Ah[3][8192], Al[3][8192];   // W tile [256n][32k] hi/lo fp16
    __shared__ ushort Bh[3][8192];                // x tile [256m][32k] fp16 (144 KiB)

    const int tid  = threadIdx.x;
    const int lane = tid & 63;
    const int wid  = tid >> 6;
    const int wr   = wid >> 2;        // n-dim wave 0..3
    const int wc   = wid & 3;         // m-dim wave 0..3
    const int m0   = blockIdx.x * 256;
    const int ng0  = blockIdx.y * 256;            // stacked n in [0,3072)
    const int p    = ng0 >> 10;
    const int n0p  = ng0 & 1023;

    const float* __restrict__ bias = (p == 0) ? bq : (p == 1 ? bk : bv);
    ushort* __restrict__ ct = qkvt + (size_t)p * HIDDEN * M_TOTAL;

    const int row = tid >> 2;         // [0,256)
    const int chS = (tid & 3) ^ ((row >> 1) & 3);   // inverse-swizzled source chunk

    const int fr = lane & 15;
    const int fc = lane >> 4;
    const int cc = (fc ^ ((fr >> 1) & 3)) * 8;

    f32x4 acc[4][4];
    #pragma unroll
    for (int rf = 0; rf < 4; ++rf)
        #pragma unroll
        for (int cf = 0; cf < 4; ++cf)
            acc[rf][cf] = (f32x4){0.f, 0.f, 0.f, 0.f};

#if HAVE_GLL
    #define QKV_STAGE(K0, SLOT) {                                                  \
        const size_t gw = (size_t)(ng0 + row) * HIDDEN + (K0) + (size_t)chS * 8;   \
        const size_t gx = (size_t)(m0 + row) * HIDDEN + (K0) + (size_t)chS * 8;    \
        gload16(wh + gw, &Ah[SLOT][(size_t)tid * 8]);                              \
        gload16(wl + gw, &Al[SLOT][(size_t)tid * 8]);                              \
        gload16(xh + gx, &Bh[SLOT][(size_t)tid * 8]);                              \
    }
#else
    #define QKV_STAGE(K0, SLOT) {                                                  \
        const size_t gw = (size_t)(ng0 + row) * HIDDEN + (K0) + (size_t)chS * 8;   \
        const size_t gx = (size_t)(m0 + row) * HIDDEN + (K0) + (size_t)chS * 8;    \
        *(f16x8*)&Ah[SLOT][(size_t)tid * 8] = *(const f16x8*)(wh + gw);            \
        *(f16x8*)&Al[SLOT][(size_t)tid * 8] = *(const f16x8*)(wl + gw);            \
        *(f16x8*)&Bh[SLOT][(size_t)tid * 8] = *(const f16x8*)(xh + gx);            \
    }
#endif

    QKV_STAGE(0, 0);
    QKV_STAGE(32, 1);

    for (int ks = 0; ks < 32; ++ks) {
        const int slot = ks % 3;
#if HAVE_GLL
        if (ks == 31) { asm volatile("s_waitcnt vmcnt(0)" ::: "memory"); }
        else          { asm volatile("s_waitcnt vmcnt(3)" ::: "memory"); }
        __builtin_amdgcn_s_barrier();
        asm volatile("" ::: "memory");      // fence: keep ds_reads below barrier
#else
        __syncthreads();
#endif
        {   // compute(ks): 32 MFMA / wave, product-major (r11-r17-validated)
            const ushort* pAh = Ah[slot];
            const ushort* pAl = Al[slot];
            const ushort* pBh = Bh[slot];
            f16x8 a_h[4], a_l[4], b_h[4];
            #pragma unroll
            for (int rf = 0; rf < 4; ++rf) {
                const int R = wr * 64 + rf * 16 + fr;
                a_h[rf] = *(const f16x8*)(pAh + R * 32 + cc);
                a_l[rf] = *(const f16x8*)(pAl + R * 32 + cc);
            }
            #pragma unroll
            for (int cf = 0; cf < 4; ++cf) {
                const int R = wc * 64 + cf * 16 + fr;
                b_h[cf] = *(const f16x8*)(pBh + R * 32 + cc);
            }
            #pragma unroll
            for (int rf = 0; rf < 4; ++rf)
                #pragma unroll
                for (int cf = 0; cf < 4; ++cf)
                    acc[rf][cf] = __builtin_amdgcn_mfma_f32_16x16x32_f16(a_h[rf], b_h[cf], acc[rf][cf], 0, 0, 0);
            #pragma unroll
            for (int rf = 0; rf < 4; ++rf)
                #pragma unroll
                for (int cf = 0; cf < 4; ++cf)
                    acc[rf][cf] = __builtin_amdgcn_mfma_f32_16x16x32_f16(a_l[rf], b_h[cf], acc[rf][cf], 0, 0, 0);
        }
        if (ks + 2 < 32) { QKV_STAGE((ks + 2) * 32, (ks + 2) % 3); }
#if !HAVE_GLL
        __syncthreads();
#endif
    }
    #undef QKV_STAGE

    // epilogue: same mapping as r7-r17, fp16 stores (halved write bytes)
    const int rq = lane >> 4;
    #pragma unroll
    for (int rf = 0; rf < 4; ++rf) {
        #pragma unroll
        for (int r = 0; r < 4; ++r) {
            const int nl = wr * 64 + rf * 16 + rq * 4 + r;
            const float bv = bias[n0p + nl];
            ushort* dst = ct + (size_t)(n0p + nl) * M_TOTAL + m0 + wc * 64;
            #pragma unroll
            for (int cf = 0; cf < 4; ++cf) {
                union { _Float16 f; ushort u; } cvt;
                cvt.f = (_Float16)(acc[rf][cf][r] + bv);
                dst[cf * 16 + fr] = cvt.u;
            }
        }
    }
}

// ---------------------------------------------------------------------------
// Radix-16 FFT machinery (math UNCHANGED r5-r17); inputs fp16 planes.
// ---------------------------------------------------------------------------
__device__ __forceinline__ float2 cmul(float2 a, float2 b) {
    return {a.x*b.x - a.y*b.y, a.x*b.y + a.y*b.x};
}

__device__ __forceinline__ int phys(int p) { return p ^ ((p >> 4) & 15); }

template<int DIR>
__device__ __forceinline__ void dft16(const float2* x, float2* X) {
    float2 t[16];
    #pragma unroll
    for (int n0 = 0; n0 < 4; ++n0) {
        float2 a = x[n0], b = x[n0+4], c = x[n0+8], d = x[n0+12];
        float2 s0 = {a.x+c.x, a.y+c.y}, s1 = {a.x-c.x, a.y-c.y};
        float2 s2 = {b.x+d.x, b.y+d.y}, s3 = {b.x-d.x, b.y-d.y};
        t[n0*4+0] = {s0.x+s2.x, s0.y+s2.y};
        t[n0*4+2] = {s0.x-s2.x, s0.y-s2.y};
        if (DIR < 0) {
            t[n0*4+1] = {s1.x+s3.y, s1.y-s3.x};
            t[n0*4+3] = {s1.x-s3.y, s1.y+s3.x};
        } else {
            t[n0*4+1] = {s1.x-s3.y, s1.y+s3.x};
            t[n0*4+3] = {s1.x+s3.y, s1.y-s3.x};
        }
    }
    const float C1 = 0.92387953251128674f;
    const float S1_ = 0.38268343236508978f;
    const float R2 = 0.70710678118654752f;
    #define TW(idx, cc_, ss_) t[idx] = cmul(t[idx], (float2){cc_, DIR*(ss_)})
    TW(1*4+1, C1, S1_);   TW(1*4+2, R2, R2);    TW(1*4+3, S1_, C1);
    TW(2*4+1, R2, R2);    TW(2*4+2, 0.f, 1.f);  TW(2*4+3, -R2, R2);
    TW(3*4+1, S1_, C1);   TW(3*4+2, -R2, R2);   TW(3*4+3, -C1, -S1_);
    #undef TW
    #pragma unroll
    for (int k0 = 0; k0 < 4; ++k0) {
        float2 a = t[0+k0], b = t[4+k0], c = t[8+k0], d = t[12+k0];
        float2 s0 = {a.x+c.x, a.y+c.y}, s1 = {a.x-c.x, a.y-c.y};
        float2 s2 = {b.x+d.x, b.y+d.y}, s3 = {b.x-d.x, b.y-d.y};
        X[k0+0]  = {s0.x+s2.x, s0.y+s2.y};
        X[k0+8]  = {s0.x-s2.x, s0.y-s2.y};
        if (DIR < 0) {
            X[k0+4]  = {s1.x+s3.y, s1.y-s3.x};
            X[k0+12] = {s1.x-s3.y, s1.y+s3.x};
        } else {
            X[k0+4]  = {s1.x-s3.y, s1.y+s3.x};
            X[k0+12] = {s1.x+s3.y, s1.y-s3.x};
        }
    }
}

__device__ __forceinline__ void twiddle_apply(float2* y, float ang) {
    float s, c;
    __sincosf(ang, &s, &c);
    const float2 base = {c, s};
    float2 w = base;
    #pragma unroll
    for (int u = 1; u < 16; ++u) {
        y[u] = cmul(y[u], w);
        w = cmul(w, base);
    }
}

__global__ __launch_bounds__(256) void fft_attn_kernel(
    const ushort* __restrict__ qt, const ushort* __restrict__ kt,
    const ushort* __restrict__ vt, float* __restrict__ ot)
{
    __shared__ float2 bufA[FFT_N];
    __shared__ float2 bufB[FFT_N];

    const int tid = threadIdx.x;
    const int bid = blockIdx.x;
    const int n   = bid >> 2;
    const int b   = bid & 3;

    const size_t off = (size_t)n * M_TOTAL + (size_t)b * SEQ;
    const _Float16* qrow = (const _Float16*)qt + off;
    const _Float16* krow = (const _Float16*)kt + off;
    const _Float16* vrow = (const _Float16*)vt + off;
    float*          orow = ot + off;

    {
        const int q = tid;
        float2 xA[16], xB[16], yA[16], yB[16];
        #pragma unroll
        for (int r = 0; r < 16; ++r) {
            xA[r] = { (float)qrow[q + 256*r], (float)krow[q + 256*r] };
            xB[r] = { (float)vrow[q + 256*r], 0.f };
        }
        dft16<-1>(xA, yA);
        dft16<-1>(xB, yB);
        const float ang = -PI2 * (float)q / 4096.f;
        twiddle_apply(yA, ang);
        twiddle_apply(yB, ang);
        #pragma unroll
        for (int u = 0; u < 16; ++u) {
            bufA[phys(q + 256*u)] = yA[u];
            bufB[phys(q + 256*u)] = yB[u];
        }
    }
    __syncthreads();
    {
        const int blk = tid >> 4, a = tid & 15;
        const int base = 256*blk + a;
        float2 xA[16], xB[16], yA[16], yB[16];
        #pragma unroll
        for (int c = 0; c < 16; ++c) {
            xA[c] = bufA[phys(base + 16*c)];
            xB[c] = bufB[phys(base + 16*c)];
        }
        dft16<-1>(xA, yA);
        dft16<-1>(xB, yB);
        const float ang = -PI2 * (float)a / 256.f;
        twiddle_apply(yA, ang);
        twiddle_apply(yB, ang);
        #pragma unroll
        for (int c = 0; c < 16; ++c) {
            bufA[phys(base + 16*c)] = yA[c];
            bufB[phys(base + 16*c)] = yB[c];
        }
    }
    __syncthreads();
    {
        const int blk = tid >> 4, c = tid & 15;
        const int base = 256*blk + 16*c;
        float2 xA[16], xB[16], yA[16], yB[16];
        #pragma unroll
        for (int a2 = 0; a2 < 16; ++a2) {
            xA[a2] = bufA[phys(base + a2)];
            xB[a2] = bufB[phys(base + a2)];
        }
        dft16<-1>(xA, yA);
        dft16<-1>(xB, yB);
        #pragma unroll
        for (int d = 0; d < 16; ++d) {
            bufA[phys(base + d)] = yA[d];
            bufB[phys(base + d)] = yB[d];
        }
    }
    __syncthreads();
    #pragma unroll
    for (int it = 0; it < 16; ++it) {
        const int p  = tid + it * 256;
        const int j  = ((p & 15) << 8) | (p & 0xF0) | (p >> 8);
        const int jn = (FFT_N - j) & (FFT_N - 1);
        const int pn = ((jn & 15) << 8) | (jn & 0xF0) | (jn >> 8);
        const float2 Zj = bufA[phys(p)];
        const float2 Zn = bufA[phys(pn)];
        const float2 Q = { 0.5f*(Zj.x + Zn.x), 0.5f*(Zj.y - Zn.y) };
        const float2 K = { 0.5f*(Zj.y + Zn.y), -0.5f*(Zj.x - Zn.x) };
        const float2 G = { Q.x*K.x + Q.y*K.y, Q.y*K.x - Q.x*K.y };
        const float2 V = bufB[phys(p)];
        bufB[phys(p)] = { G.x*V.x - G.y*V.y, G.x*V.y + G.y*V.x };
    }
    __syncthreads();
    {
        const int blk = tid >> 4, c = tid & 15;
        const int base = 256*blk + 16*c;
        float2 x[16], y[16];
        #pragma unroll
        for (int d = 0; d < 16; ++d) x[d] = bufB[phys(base + d)];
        dft16<1>(x, y);
        #pragma unroll
        for (int p0 = 0; p0 < 16; ++p0) bufB[phys(base + p0)] = y[p0];
    }
    __syncthreads();
    {
        const int blk = tid >> 4, p0 = tid & 15;
        const int base = 256*blk + p0;
        float2 x[16], y[16];
        #pragma unroll
        for (int c = 0; c < 16; ++c) x[c] = bufB[phys(base + 16*c)];
        twiddle_apply(x, PI2 * (float)p0 / 256.f);
        dft16<1>(x, y);
        #pragma unroll
        for (int p1 = 0; p1 < 16; ++p1) bufB[phys(base + 16*p1)] = y[p1];
    }
    __syncthreads();
    {
        const int qq = tid;
        float2 x[16], y[16];
        #pragma unroll
        for (int t = 0; t < 16; ++t) x[t] = bufB[phys(qq + 256*t)];
        twiddle_apply(x, PI2 * (float)qq / 4096.f);
        dft16<1>(x, y);
        const float scale = 0.125f / 4096.f;
        #pragma unroll
        for (int p2 = 0; p2 < 16; ++p2)
            orow[qq + 256*p2] = y[p2].x * scale;
    }
}

// ---------------------------------------------------------------------------
// Transpose + fp16 split (UNCHANGED, validated r11-r17)
// ---------------------------------------------------------------------------
__global__ __launch_bounds__(256) void transpose_split_kernel(
    const float* __restrict__ ot, ushort* __restrict__ oth,
    ushort* __restrict__ otl)
{
    __shared__ float tile[64][65];
    const int tid = threadIdx.x;
    const int m0  = blockIdx.x * 64;
    const int n0  = blockIdx.y * 64;
    const int r   = tid >> 4;
    const int c   = tid & 15;

    #pragma unroll
    for (int rr = 0; rr < 4; ++rr) {
        const int nl = r + rr * 16;
        float4 v = *(const float4*)(ot + (size_t)(n0 + nl) * M_TOTAL + m0 + c * 4);
        tile[nl][c * 4 + 0] = v.x; tile[nl][c * 4 + 1] = v.y;
        tile[nl][c * 4 + 2] = v.z; tile[nl][c * 4 + 3] = v.w;
    }
    __syncthreads();
    #pragma unroll
    for (int rr = 0; rr < 4; ++rr) {
        const int ml = r + rr * 16;
        ushort4 hh, ll;
        split1_f16(tile[c * 4 + 0][ml], hh.x, ll.x);
        split1_f16(tile[c * 4 + 1][ml], hh.y, ll.y);
        split1_f16(tile[c * 4 + 2][ml], hh.z, ll.z);
        split1_f16(tile[c * 4 + 3][ml], hh.w, ll.w);
        *(ushort4*)(oth + (size_t)(m0 + ml) * HIDDEN + n0 + c * 4) = hh;
        *(ushort4*)(otl + (size_t)(m0 + ml) * HIDDEN + n0 + c * 4) = ll;
    }
}

// ---------------------------------------------------------------------------
// Output GEMM (MFMA fp16, gload16 staging, triple-buffer + counted vmcnt)
// r15/r17-exact structure. 256 blocks.
// ---------------------------------------------------------------------------
__global__ __launch_bounds__(1024, 1) void gemm_out_mfma7(
    const ushort* __restrict__ oth, const ushort* __restrict__ otl,
    const ushort* __restrict__ woh, const float* __restrict__ bo,
    float* __restrict__ out)
{
    __shared__ ushort Ah[3][8192], Al[3][8192];   // ot^T tile [256m][32k] hi/lo
    __shared__ ushort Bh[3][8192];                // Wo tile [256n][32k] fp16

    const int tid  = threadIdx.x;
    const int lane = tid & 63;
    const int wid  = tid >> 6;
    const int wr   = wid >> 2;        // m-dim wave
    const int wc   = wid & 3;         // n-dim wave
    const int m0   = blockIdx.x * 256;
    const int n0   = blockIdx.y * 256;

    const int row = tid >> 2;
    const int chS = (tid & 3) ^ ((row >> 1) & 3);

    const int fr = lane & 15;
    const int fc = lane >> 4;
    const int cc = (fc ^ ((fr >> 1) & 3)) * 8;

    f32x4 acc[4][4];
    #pragma unroll
    for (int rf = 0; rf < 4; ++rf)
        #pragma unroll
        for (int cf = 0; cf < 4; ++cf)
            acc[rf][cf] = (f32x4){0.f, 0.f, 0.f, 0.f};

#if HAVE_GLL
    #define OUT_STAGE(K0, SLOT) {                                                  \
        const size_t ga = (size_t)(m0 + row) * HIDDEN + (K0) + (size_t)chS * 8;    \
        const size_t gb = (size_t)(n0 + row) * HIDDEN + (K0) + (size_t)chS * 8;    \
        gload16(oth + ga, &Ah[SLOT][(size_t)tid * 8]);                             \
        gload16(otl + ga, &Al[SLOT][(size_t)tid * 8]);                             \
        gload16(woh + gb, &Bh[SLOT][(size_t)tid * 8]);                             \
    }
#else
    #define OUT_STAGE(K0, SLOT) {                                                  \
        const size_t ga = (size_t)(m0 + row) * HIDDEN + (K0) + (size_t)chS * 8;    \
        const size_t gb = (size_t)(n0 + row) * HIDDEN + (K0) + (size_t)chS * 8;    \
        *(f16x8*)&Ah[SLOT][(size_t)tid * 8] = *(const f16x8*)(oth + ga);           \
        *(f16x8*)&Al[SLOT][(size_t)tid * 8] = *(const f16x8*)(otl + ga);           \
        *(f16x8*)&Bh[SLOT][(size_t)tid * 8] = *(const f16x8*)(woh + gb);           \
    }
#endif

    OUT_STAGE(0, 0);
    OUT_STAGE(32, 1);

    for (int ks = 0; ks < 32; ++ks) {
        const int slot = ks % 3;
#if HAVE_GLL
        if (ks == 31) { asm volatile("s_waitcnt vmcnt(0)" ::: "memory"); }
        else          { asm volatile("s_waitcnt vmcnt(3)" ::: "memory"); }
        __builtin_amdgcn_s_barrier();
        asm volatile("" ::: "memory");
#else
        __syncthreads();
#endif
        {
            const ushort* pAh = Ah[slot];
            const ushort* pAl = Al[slot];
            const ushort* pBh = Bh[slot];
            f16x8 a_h[4], a_l[4], b_h[4];
            #pragma unroll
            for (int rf = 0; rf < 4; ++rf) {
                const int R = wr * 64 + rf * 16 + fr;
                a_h[rf] = *(const f16x8*)(pAh + R * 32 + cc);
                a_l[rf] = *(const f16x8*)(pAl + R * 32 + cc);
            }
            #pragma unroll
            for (int cf = 0; cf < 4; ++cf) {
                const int R = wc * 64 + cf * 16 + fr;
                b_h[cf] = *(const f16x8*)(pBh + R * 32 + cc);
            }
            #pragma unroll
            for (int rf = 0; rf < 4; ++rf)
                #pragma unroll
                for (int cf = 0; cf < 4; ++cf)
                    acc[rf][cf] = __builtin_amdgcn_mfma_f32_16x16x32_f16(a_h[rf], b_h[cf], acc[rf][cf], 0, 0, 0);
            #pragma unroll
            for (int rf = 0; rf < 4; ++rf)
                #pragma unroll
                for (int cf = 0; cf < 4; ++cf)
                    acc[rf][cf] = __builtin_amdgcn_mfma_f32_16x16x32_f16(a_l[rf], b_h[cf], acc[rf][cf], 0, 0, 0);
        }
        if (ks + 2 < 32) { OUT_STAGE((ks + 2) * 32, (ks + 2) % 3); }
#if !HAVE_GLL
        __syncthreads();
#endif
    }
    #undef OUT_STAGE

    // epilogue: D row m_local = wr*64+rf*16+rq*4+r ; col n_local = wc*64+cf*16+fr
    const int rq = lane >> 4;
    float bo_v[4];
    #pragma unroll
    for (int cf = 0; cf < 4; ++cf) bo_v[cf] = bo[n0 + wc * 64 + cf * 16 + fr];
    #pragma unroll
    for (int rf = 0; rf < 4; ++rf) {
        #pragma unroll
        for (int r = 0; r < 4; ++r) {
            const int ml = wr * 64 + rf * 16 + rq * 4 + r;
            float* dst = out + (size_t)(m0 + ml) * HIDDEN + n0 + wc * 64;
            #pragma unroll
            for (int cf = 0; cf < 4; ++cf)
                dst[cf * 16 + fr] = acc[rf][cf][r] + bo_v[cf];
        }
    }
}

// ---------------------------------------------------------------------------
// Buffers (ws = proven 201.3 MB; peak use 169.9 MB):
//   ws[0..100.66M):        qkvt fp16 [3][1024][16384]
//   ws[100.66..167.77M):   ot fp32 [1024][16384]
//   ws[167.77..169.87M):   woh fp16 [1024][1024]   (ws, NOT d_out -- r18 race fix)
//   After fft: oth/otl (67.1 MB) alias the dead qkvt fp16 region.
//   d_out stash: xh 33.55 + wh 6.29 + wl 6.29 = 46.1 MB < 67.1; dead before
//   gemm_out writes d_out.
// ---------------------------------------------------------------------------
extern "C" void kernel_launch(void* const* d_in, const int* in_sizes, int n_in,
                              void* d_out, int out_size, void* d_ws, size_t ws_size,
                              hipStream_t stream)
{
    const float* x  = (const float*)d_in[0];
    const float* Wq = (const float*)d_in[1];
    const float* bq = (const float*)d_in[2];
    const float* Wk = (const float*)d_in[3];
    const float* bk = (const float*)d_in[4];
    const float* Wv = (const float*)d_in[5];
    const float* bv = (const float*)d_in[6];
    const float* Wo = (const float*)d_in[7];
    const float* bo = (const float*)d_in[8];
    float* out = (float*)d_out;

    const size_t plane = (size_t)HIDDEN * M_TOTAL;   // 16.78M elements
    ushort* qkvt = (ushort*)d_ws;                    // fp16 [3][1024][16384]
    ushort* qt16 = qkvt;
    ushort* kt16 = qkvt + plane;
    ushort* vt16 = qkvt + 2 * plane;
    float*  ot   = (float*)((char*)d_ws + 3 * plane * 2);   // fp32 [1024][16384]
    ushort* woh  = (ushort*)((char*)d_ws + 3 * plane * 2 + plane * 4);  // fp16 [1024][1024]

    // post-fft stash aliases dead qkvt fp16 region (100.66 MB >= 67.1)
    ushort* oth = qkvt;                              // [16384][1024] fp16 hi
    ushort* otl = qkvt + plane;                      // lo

    // fp16 operand stash in d_out (dead before gemm_out writes d_out)
    ushort* xh  = (ushort*)d_out;                    // [16384][1024]
    ushort* wh  = xh + plane;                        // stacked [3072][1024]
    ushort* wl  = wh + 3 * WSZ;

    // pre-passes: x -> fp16; Wq/Wk/Wv split + Wo cvt in ONE launch
    cvt16_kernel<<<(unsigned)(plane / 2048), 256, 0, stream>>>(x, xh);
    splitW_kernel<<<dim3((unsigned)(WSZ / 2048), 4), 256, 0, stream>>>(
        Wq, Wk, Wv, Wo, wh, wl, woh);

    // QKV projections (full batch, 768 blocks = 3x256) -> fp16 planes
    gemm_qkv_mfma7<<<dim3(M_TOTAL / 256, 12), 1024, 0, stream>>>(
        xh, wh, wl, bq, bk, bv, qkvt);

    // FFT attention (fp16 in, fp32 out)
    fft_attn_kernel<<<dim3(HIDDEN * BATCH), 256, 0, stream>>>(
        qt16, kt16, vt16, ot);

    // transpose ot -> fp16 hi/lo [m][k] into dead qkvt region
    transpose_split_kernel<<<dim3(M_TOTAL / 64, HIDDEN / 64), 256, 0, stream>>>(
        ot, oth, otl);

    // output projection (256 blocks, overwrites d_out)
    gemm_out_mfma7<<<dim3(M_TOTAL / 256, HIDDEN / 256), 1024, 0, stream>>>(
        oth, otl, woh, bo, out);
}

// Round 20
// 276.124 us; speedup vs baseline: 1.4483x; 1.3364x over previous
//
#include <hip/hip_runtime.h>
#include <hip/hip_bf16.h>
#include <math.h>

#define HIDDEN   1024
#define HEADS    16
#define HEAD_DIM 64
#define BATCH    4
#define SEQ      4096
#define M_TOTAL  (BATCH * SEQ)          // 16384
#define FFT_N    4096
#define WSZ      ((size_t)HIDDEN * HIDDEN)
#define PI2      6.28318530717958647692f

typedef _Float16 f16x8 __attribute__((ext_vector_type(8)));   // 8 fp16 = 4 VGPR (MFMA A/B frag)
typedef float    f32x4 __attribute__((ext_vector_type(4)));   // MFMA C/D frag

#if defined(__has_builtin)
#if __has_builtin(__builtin_amdgcn_global_load_lds)
#define HAVE_GLL 1
#else
#define HAVE_GLL 0
#endif
#else
#define HAVE_GLL 0
#endif

#if HAVE_GLL
// async global->LDS, 16B/lane. dest = wave-uniform base + lane*16 (linear in slot).
__device__ __forceinline__ void gload16(const void* g, void* l) {
    __builtin_amdgcn_global_load_lds(
        (const __attribute__((address_space(1))) unsigned int*)g,
        (__attribute__((address_space(3))) unsigned int*)l,
        16, 0, 0);
}
#endif

__device__ __forceinline__ void cvt8_f16(float4 v0, float4 v1,
                                         ushort* __restrict__ d) {
    const float vv[8] = {v0.x, v0.y, v0.z, v0.w, v1.x, v1.y, v1.z, v1.w};
    f16x8 hv;
    #pragma unroll
    for (int e = 0; e < 8; ++e) hv[e] = (_Float16)vv[e];
    *(f16x8*)d = hv;
}

// ---------------------------------------------------------------------------
// Pre-pass kernels: x -> fp16; all four W -> single fp16 in ONE launch
// (blockIdx.y: 0..2 = Wq/Wk/Wv -> wh stacked; 3 = Wo -> woh).
// 1-product pure-fp16 pipeline this round: lo planes dropped everywhere
// (error budget: absmax 16 vs threshold 61.44; each fp16 rounding source
// historically adds ~8).
// ---------------------------------------------------------------------------
__global__ __launch_bounds__(256) void cvt16_kernel(
    const float* __restrict__ src, ushort* __restrict__ h)
{
    const size_t i = ((size_t)blockIdx.x * 256 + threadIdx.x) * 8;
    float4 v0 = *(const float4*)(src + i);
    float4 v1 = *(const float4*)(src + i + 4);
    cvt8_f16(v0, v1, h + i);
}

__global__ __launch_bounds__(256) void cvtW_kernel(
    const float* __restrict__ Wq, const float* __restrict__ Wk,
    const float* __restrict__ Wv, const float* __restrict__ Wo,
    ushort* __restrict__ wh, ushort* __restrict__ woh)
{
    const int p = blockIdx.y;                 // 0=q 1=k 2=v 3=o
    const size_t i = ((size_t)blockIdx.x * 256 + threadIdx.x) * 8;
    const float* __restrict__ src = (p == 0) ? Wq : (p == 1 ? Wk : (p == 2 ? Wv : Wo));
    ushort* __restrict__ dst = (p < 3) ? (wh + (size_t)p * WSZ) : woh;
    float4 v0 = *(const float4*)(src + i);
    float4 v1 = *(const float4*)(src + i + 4);
    cvt8_f16(v0, v1, dst + i);
}

// ---------------------------------------------------------------------------
// QKV GEMM (MFMA fp16 1-product, gload16 staging, 3-slot + counted vmcnt):
//   ct[p][n][m] = sum_k W16[ng][k] * x16[m][k]   (fp16 store)
// K-loop STRUCTURE byte-equivalent to r15/r17/r19-validated form; only the
// lo-plane operands removed: 2 gloads/stage -> vmcnt(2) certifies tile t
// (STAGE(t+1)'s 2 loads stay in flight). 16 MFMA + 8 ds_read_b128 / wave.
// LDS 96 KiB (3 slots x [A 16KB + B 16KB]).
// ---------------------------------------------------------------------------
__global__ __launch_bounds__(1024, 1) void gemm_qkv_mfma8(
    const ushort* __restrict__ xh, const ushort* __restrict__ wh,
    const float* __restrict__ bq, const float* __restrict__ bk,
    const float* __restrict__ bv,
    ushort* __restrict__ qkvt)
{
    __shared__ ushort Ah[3][8192];   // W tile [256n][32k] fp16
    __shared__ ushort Bh[3][8192];   // x tile [256m][32k] fp16 (96 KiB total)

    const int tid  = threadIdx.x;
    const int lane = tid & 63;
    const int wid  = tid >> 6;
    const int wr   = wid >> 2;        // n-dim wave 0..3
    const int wc   = wid & 3;         // m-dim wave 0..3
    const int m0   = blockIdx.x * 256;
    const int ng0  = blockIdx.y * 256;            // stacked n in [0,3072)
    const int p    = ng0 >> 10;
    const int n0p  = ng0 & 1023;

    const float* __restrict__ bias = (p == 0) ? bq : (p == 1 ? bk : bv);
    ushort* __restrict__ ct = qkvt + (size_t)p * HIDDEN * M_TOTAL;

    const int row = tid >> 2;         // [0,256)
    const int chS = (tid & 3) ^ ((row >> 1) & 3);   // inverse-swizzled source chunk

    const int fr = lane & 15;
    const int fc = lane >> 4;
    const int cc = (fc ^ ((fr >> 1) & 3)) * 8;

    f32x4 acc[4][4];
    #pragma unroll
    for (int rf = 0; rf < 4; ++rf)
        #pragma unroll
        for (int cf = 0; cf < 4; ++cf)
            acc[rf][cf] = (f32x4){0.f, 0.f, 0.f, 0.f};

#if HAVE_GLL
    #define QKV_STAGE(K0, SLOT) {                                                  \
        const size_t gw = (size_t)(ng0 + row) * HIDDEN + (K0) + (size_t)chS * 8;   \
        const size_t gx = (size_t)(m0 + row) * HIDDEN + (K0) + (size_t)chS * 8;    \
        gload16(wh + gw, &Ah[SLOT][(size_t)tid * 8]);                              \
        gload16(xh + gx, &Bh[SLOT][(size_t)tid * 8]);                              \
    }
#else
    #define QKV_STAGE(K0, SLOT) {                                                  \
        const size_t gw = (size_t)(ng0 + row) * HIDDEN + (K0) + (size_t)chS * 8;   \
        const size_t gx = (size_t)(m0 + row) * HIDDEN + (K0) + (size_t)chS * 8;    \
        *(f16x8*)&Ah[SLOT][(size_t)tid * 8] = *(const f16x8*)(wh + gw);            \
        *(f16x8*)&Bh[SLOT][(size_t)tid * 8] = *(const f16x8*)(xh + gx);            \
    }
#endif

    QKV_STAGE(0, 0);
    QKV_STAGE(32, 1);

    for (int ks = 0; ks < 32; ++ks) {
        const int slot = ks % 3;
#if HAVE_GLL
        if (ks == 31) { asm volatile("s_waitcnt vmcnt(0)" ::: "memory"); }
        else          { asm volatile("s_waitcnt vmcnt(2)" ::: "memory"); }
        __builtin_amdgcn_s_barrier();
        asm volatile("" ::: "memory");      // fence: keep ds_reads below barrier
#else
        __syncthreads();
#endif
        {   // compute(ks): 16 MFMA / wave, product-major
            const ushort* pAh = Ah[slot];
            const ushort* pBh = Bh[slot];
            f16x8 a_h[4], b_h[4];
            #pragma unroll
            for (int rf = 0; rf < 4; ++rf) {
                const int R = wr * 64 + rf * 16 + fr;
                a_h[rf] = *(const f16x8*)(pAh + R * 32 + cc);
            }
            #pragma unroll
            for (int cf = 0; cf < 4; ++cf) {
                const int R = wc * 64 + cf * 16 + fr;
                b_h[cf] = *(const f16x8*)(pBh + R * 32 + cc);
            }
            #pragma unroll
            for (int rf = 0; rf < 4; ++rf)
                #pragma unroll
                for (int cf = 0; cf < 4; ++cf)
                    acc[rf][cf] = __builtin_amdgcn_mfma_f32_16x16x32_f16(a_h[rf], b_h[cf], acc[rf][cf], 0, 0, 0);
        }
        if (ks + 2 < 32) { QKV_STAGE((ks + 2) * 32, (ks + 2) % 3); }
#if !HAVE_GLL
        __syncthreads();
#endif
    }
    #undef QKV_STAGE

    // epilogue (r19-validated): fp16 stores; row n_local = wr*64+rf*16+rq*4+r
    const int rq = lane >> 4;
    #pragma unroll
    for (int rf = 0; rf < 4; ++rf) {
        #pragma unroll
        for (int r = 0; r < 4; ++r) {
            const int nl = wr * 64 + rf * 16 + rq * 4 + r;
            const float bv = bias[n0p + nl];
            ushort* dst = ct + (size_t)(n0p + nl) * M_TOTAL + m0 + wc * 64;
            #pragma unroll
            for (int cf = 0; cf < 4; ++cf) {
                union { _Float16 f; ushort u; } cvt;
                cvt.f = (_Float16)(acc[rf][cf][r] + bv);
                dst[cf * 16 + fr] = cvt.u;
            }
        }
    }
}

// ---------------------------------------------------------------------------
// Radix-16 FFT machinery (math UNCHANGED r5-r19); fp16 in, fp32 out.
// ---------------------------------------------------------------------------
__device__ __forceinline__ float2 cmul(float2 a, float2 b) {
    return {a.x*b.x - a.y*b.y, a.x*b.y + a.y*b.x};
}

__device__ __forceinline__ int phys(int p) { return p ^ ((p >> 4) & 15); }

template<int DIR>
__device__ __forceinline__ void dft16(const float2* x, float2* X) {
    float2 t[16];
    #pragma unroll
    for (int n0 = 0; n0 < 4; ++n0) {
        float2 a = x[n0], b = x[n0+4], c = x[n0+8], d = x[n0+12];
        float2 s0 = {a.x+c.x, a.y+c.y}, s1 = {a.x-c.x, a.y-c.y};
        float2 s2 = {b.x+d.x, b.y+d.y}, s3 = {b.x-d.x, b.y-d.y};
        t[n0*4+0] = {s0.x+s2.x, s0.y+s2.y};
        t[n0*4+2] = {s0.x-s2.x, s0.y-s2.y};
        if (DIR < 0) {
            t[n0*4+1] = {s1.x+s3.y, s1.y-s3.x};
            t[n0*4+3] = {s1.x-s3.y, s1.y+s3.x};
        } else {
            t[n0*4+1] = {s1.x-s3.y, s1.y+s3.x};
            t[n0*4+3] = {s1.x+s3.y, s1.y-s3.x};
        }
    }
    const float C1 = 0.92387953251128674f;
    const float S1_ = 0.38268343236508978f;
    const float R2 = 0.70710678118654752f;
    #define TW(idx, cc_, ss_) t[idx] = cmul(t[idx], (float2){cc_, DIR*(ss_)})
    TW(1*4+1, C1, S1_);   TW(1*4+2, R2, R2);    TW(1*4+3, S1_, C1);
    TW(2*4+1, R2, R2);    TW(2*4+2, 0.f, 1.f);  TW(2*4+3, -R2, R2);
    TW(3*4+1, S1_, C1);   TW(3*4+2, -R2, R2);   TW(3*4+3, -C1, -S1_);
    #undef TW
    #pragma unroll
    for (int k0 = 0; k0 < 4; ++k0) {
        float2 a = t[0+k0], b = t[4+k0], c = t[8+k0], d = t[12+k0];
        float2 s0 = {a.x+c.x, a.y+c.y}, s1 = {a.x-c.x, a.y-c.y};
        float2 s2 = {b.x+d.x, b.y+d.y}, s3 = {b.x-d.x, b.y-d.y};
        X[k0+0]  = {s0.x+s2.x, s0.y+s2.y};
        X[k0+8]  = {s0.x-s2.x, s0.y-s2.y};
        if (DIR < 0) {
            X[k0+4]  = {s1.x+s3.y, s1.y-s3.x};
            X[k0+12] = {s1.x-s3.y, s1.y+s3.x};
        } else {
            X[k0+4]  = {s1.x-s3.y, s1.y+s3.x};
            X[k0+12] = {s1.x+s3.y, s1.y-s3.x};
        }
    }
}

__device__ __forceinline__ void twiddle_apply(float2* y, float ang) {
    float s, c;
    __sincosf(ang, &s, &c);
    const float2 base = {c, s};
    float2 w = base;
    #pragma unroll
    for (int u = 1; u < 16; ++u) {
        y[u] = cmul(y[u], w);
        w = cmul(w, base);
    }
}

__global__ __launch_bounds__(256) void fft_attn_kernel(
    const ushort* __restrict__ qt, const ushort* __restrict__ kt,
    const ushort* __restrict__ vt, float* __restrict__ ot)
{
    __shared__ float2 bufA[FFT_N];
    __shared__ float2 bufB[FFT_N];

    const int tid = threadIdx.x;
    const int bid = blockIdx.x;
    const int n   = bid >> 2;
    const int b   = bid & 3;

    const size_t off = (size_t)n * M_TOTAL + (size_t)b * SEQ;
    const _Float16* qrow = (const _Float16*)qt + off;
    const _Float16* krow = (const _Float16*)kt + off;
    const _Float16* vrow = (const _Float16*)vt + off;
    float*          orow = ot + off;

    {
        const int q = tid;
        float2 xA[16], xB[16], yA[16], yB[16];
        #pragma unroll
        for (int r = 0; r < 16; ++r) {
            xA[r] = { (float)qrow[q + 256*r], (float)krow[q + 256*r] };
            xB[r] = { (float)vrow[q + 256*r], 0.f };
        }
        dft16<-1>(xA, yA);
        dft16<-1>(xB, yB);
        const float ang = -PI2 * (float)q / 4096.f;
        twiddle_apply(yA, ang);
        twiddle_apply(yB, ang);
        #pragma unroll
        for (int u = 0; u < 16; ++u) {
            bufA[phys(q + 256*u)] = yA[u];
            bufB[phys(q + 256*u)] = yB[u];
        }
    }
    __syncthreads();
    {
        const int blk = tid >> 4, a = tid & 15;
        const int base = 256*blk + a;
        float2 xA[16], xB[16], yA[16], yB[16];
        #pragma unroll
        for (int c = 0; c < 16; ++c) {
            xA[c] = bufA[phys(base + 16*c)];
            xB[c] = bufB[phys(base + 16*c)];
        }
        dft16<-1>(xA, yA);
        dft16<-1>(xB, yB);
        const float ang = -PI2 * (float)a / 256.f;
        twiddle_apply(yA, ang);
        twiddle_apply(yB, ang);
        #pragma unroll
        for (int c = 0; c < 16; ++c) {
            bufA[phys(base + 16*c)] = yA[c];
            bufB[phys(base + 16*c)] = yB[c];
        }
    }
    __syncthreads();
    {
        const int blk = tid >> 4, c = tid & 15;
        const int base = 256*blk + 16*c;
        float2 xA[16], xB[16], yA[16], yB[16];
        #pragma unroll
        for (int a2 = 0; a2 < 16; ++a2) {
            xA[a2] = bufA[phys(base + a2)];
            xB[a2] = bufB[phys(base + a2)];
        }
        dft16<-1>(xA, yA);
        dft16<-1>(xB, yB);
        #pragma unroll
        for (int d = 0; d < 16; ++d) {
            bufA[phys(base + d)] = yA[d];
            bufB[phys(base + d)] = yB[d];
        }
    }
    __syncthreads();
    #pragma unroll
    for (int it = 0; it < 16; ++it) {
        const int p  = tid + it * 256;
        const int j  = ((p & 15) << 8) | (p & 0xF0) | (p >> 8);
        const int jn = (FFT_N - j) & (FFT_N - 1);
        const int pn = ((jn & 15) << 8) | (jn & 0xF0) | (jn >> 8);
        const float2 Zj = bufA[phys(p)];
        const float2 Zn = bufA[phys(pn)];
        const float2 Q = { 0.5f*(Zj.x + Zn.x), 0.5f*(Zj.y - Zn.y) };
        const float2 K = { 0.5f*(Zj.y + Zn.y), -0.5f*(Zj.x - Zn.x) };
        const float2 G = { Q.x*K.x + Q.y*K.y, Q.y*K.x - Q.x*K.y };
        const float2 V = bufB[phys(p)];
        bufB[phys(p)] = { G.x*V.x - G.y*V.y, G.x*V.y + G.y*V.x };
    }
    __syncthreads();
    {
        const int blk = tid >> 4, c = tid & 15;
        const int base = 256*blk + 16*c;
        float2 x[16], y[16];
        #pragma unroll
        for (int d = 0; d < 16; ++d) x[d] = bufB[phys(base + d)];
        dft16<1>(x, y);
        #pragma unroll
        for (int p0 = 0; p0 < 16; ++p0) bufB[phys(base + p0)] = y[p0];
    }
    __syncthreads();
    {
        const int blk = tid >> 4, p0 = tid & 15;
        const int base = 256*blk + p0;
        float2 x[16], y[16];
        #pragma unroll
        for (int c = 0; c < 16; ++c) x[c] = bufB[phys(base + 16*c)];
        twiddle_apply(x, PI2 * (float)p0 / 256.f);
        dft16<1>(x, y);
        #pragma unroll
        for (int p1 = 0; p1 < 16; ++p1) bufB[phys(base + 16*p1)] = y[p1];
    }
    __syncthreads();
    {
        const int qq = tid;
        float2 x[16], y[16];
        #pragma unroll
        for (int t = 0; t < 16; ++t) x[t] = bufB[phys(qq + 256*t)];
        twiddle_apply(x, PI2 * (float)qq / 4096.f);
        dft16<1>(x, y);
        const float scale = 0.125f / 4096.f;
        #pragma unroll
        for (int p2 = 0; p2 < 16; ++p2)
            orow[qq + 256*p2] = y[p2].x * scale;
    }
}

// ---------------------------------------------------------------------------
// Transpose + fp16 cvt (single plane): ot fp32 [n][m] -> oth fp16 [m][k=n]
// (r11-r19 tile pattern; lo plane dropped)
// ---------------------------------------------------------------------------
__global__ __launch_bounds__(256) void transpose_cvt_kernel(
    const float* __restrict__ ot, ushort* __restrict__ oth)
{
    __shared__ float tile[64][65];
    const int tid = threadIdx.x;
    const int m0  = blockIdx.x * 64;
    const int n0  = blockIdx.y * 64;
    const int r   = tid >> 4;
    const int c   = tid & 15;

    #pragma unroll
    for (int rr = 0; rr < 4; ++rr) {
        const int nl = r + rr * 16;
        float4 v = *(const float4*)(ot + (size_t)(n0 + nl) * M_TOTAL + m0 + c * 4);
        tile[nl][c * 4 + 0] = v.x; tile[nl][c * 4 + 1] = v.y;
        tile[nl][c * 4 + 2] = v.z; tile[nl][c * 4 + 3] = v.w;
    }
    __syncthreads();
    #pragma unroll
    for (int rr = 0; rr < 4; ++rr) {
        const int ml = r + rr * 16;
        ushort4 hh;
        union { _Float16 f; ushort u; } cv;
        cv.f = (_Float16)tile[c * 4 + 0][ml]; hh.x = cv.u;
        cv.f = (_Float16)tile[c * 4 + 1][ml]; hh.y = cv.u;
        cv.f = (_Float16)tile[c * 4 + 2][ml]; hh.z = cv.u;
        cv.f = (_Float16)tile[c * 4 + 3][ml]; hh.w = cv.u;
        *(ushort4*)(oth + (size_t)(m0 + ml) * HIDDEN + n0 + c * 4) = hh;
    }
}

// ---------------------------------------------------------------------------
// Output GEMM (MFMA fp16 1-product, gload16 staging, 3-slot counted vmcnt)
// out[m][n] = oth[m][:].woh[n][:] + bo[n].  Same validated structure.
// ---------------------------------------------------------------------------
__global__ __launch_bounds__(1024, 1) void gemm_out_mfma8(
    const ushort* __restrict__ oth, const ushort* __restrict__ woh,
    const float* __restrict__ bo, float* __restrict__ out)
{
    __shared__ ushort Ah[3][8192];   // ot^T tile [256m][32k] fp16
    __shared__ ushort Bh[3][8192];   // Wo tile [256n][32k] fp16

    const int tid  = threadIdx.x;
    const int lane = tid & 63;
    const int wid  = tid >> 6;
    const int wr   = wid >> 2;        // m-dim wave
    const int wc   = wid & 3;         // n-dim wave
    const int m0   = blockIdx.x * 256;
    const int n0   = blockIdx.y * 256;

    const int row = tid >> 2;
    const int chS = (tid & 3) ^ ((row >> 1) & 3);

    const int fr = lane & 15;
    const int fc = lane >> 4;
    const int cc = (fc ^ ((fr >> 1) & 3)) * 8;

    f32x4 acc[4][4];
    #pragma unroll
    for (int rf = 0; rf < 4; ++rf)
        #pragma unroll
        for (int cf = 0; cf < 4; ++cf)
            acc[rf][cf] = (f32x4){0.f, 0.f, 0.f, 0.f};

#if HAVE_GLL
    #define OUT_STAGE(K0, SLOT) {                                                  \
        const size_t ga = (size_t)(m0 + row) * HIDDEN + (K0) + (size_t)chS * 8;    \
        const size_t gb = (size_t)(n0 + row) * HIDDEN + (K0) + (size_t)chS * 8;    \
        gload16(oth + ga, &Ah[SLOT][(size_t)tid * 8]);                             \
        gload16(woh + gb, &Bh[SLOT][(size_t)tid * 8]);                             \
    }
#else
    #define OUT_STAGE(K0, SLOT) {                                                  \
        const size_t ga = (size_t)(m0 + row) * HIDDEN + (K0) + (size_t)chS * 8;    \
        const size_t gb = (size_t)(n0 + row) * HIDDEN + (K0) + (size_t)chS * 8;    \
        *(f16x8*)&Ah[SLOT][(size_t)tid * 8] = *(const f16x8*)(oth + ga);           \
        *(f16x8*)&Bh[SLOT][(size_t)tid * 8] = *(const f16x8*)(woh + gb);           \
    }
#endif

    OUT_STAGE(0, 0);
    OUT_STAGE(32, 1);

    for (int ks = 0; ks < 32; ++ks) {
        const int slot = ks % 3;
#if HAVE_GLL
        if (ks == 31) { asm volatile("s_waitcnt vmcnt(0)" ::: "memory"); }
        else          { asm volatile("s_waitcnt vmcnt(2)" ::: "memory"); }
        __builtin_amdgcn_s_barrier();
        asm volatile("" ::: "memory");
#else
        __syncthreads();
#endif
        {
            const ushort* pAh = Ah[slot];
            const ushort* pBh = Bh[slot];
            f16x8 a_h[4], b_h[4];
            #pragma unroll
            for (int rf = 0; rf < 4; ++rf) {
                const int R = wr * 64 + rf * 16 + fr;
                a_h[rf] = *(const f16x8*)(pAh + R * 32 + cc);
            }
            #pragma unroll
            for (int cf = 0; cf < 4; ++cf) {
                const int R = wc * 64 + cf * 16 + fr;
                b_h[cf] = *(const f16x8*)(pBh + R * 32 + cc);
            }
            #pragma unroll
            for (int rf = 0; rf < 4; ++rf)
                #pragma unroll
                for (int cf = 0; cf < 4; ++cf)
                    acc[rf][cf] = __builtin_amdgcn_mfma_f32_16x16x32_f16(a_h[rf], b_h[cf], acc[rf][cf], 0, 0, 0);
        }
        if (ks + 2 < 32) { OUT_STAGE((ks + 2) * 32, (ks + 2) % 3); }
#if !HAVE_GLL
        __syncthreads();
#endif
    }
    #undef OUT_STAGE

    // epilogue: D row m_local = wr*64+rf*16+rq*4+r ; col n_local = wc*64+cf*16+fr
    const int rq = lane >> 4;
    float bo_v[4];
    #pragma unroll
    for (int cf = 0; cf < 4; ++cf) bo_v[cf] = bo[n0 + wc * 64 + cf * 16 + fr];
    #pragma unroll
    for (int rf = 0; rf < 4; ++rf) {
        #pragma unroll
        for (int r = 0; r < 4; ++r) {
            const int ml = wr * 64 + rf * 16 + rq * 4 + r;
            float* dst = out + (size_t)(m0 + ml) * HIDDEN + n0 + wc * 64;
            #pragma unroll
            for (int cf = 0; cf < 4; ++cf)
                dst[cf * 16 + fr] = acc[rf][cf][r] + bo_v[cf];
        }
    }
}

// ---------------------------------------------------------------------------
// Buffers (ws = proven 201.3 MB; peak use 169.9 MB):
//   ws[0..100.66M):        qkvt fp16 [3][1024][16384]
//   ws[100.66..167.77M):   ot fp32 [1024][16384]
//   ws[167.77..169.87M):   woh fp16 [1024][1024]   (ws, NOT d_out -- r18 lesson)
//   After fft: oth (33.5 MB) aliases the dead qkvt fp16 region.
//   d_out stash: xh 33.55 + wh 6.29 = 39.8 MB < 67.1; dead before gemm_out
//   writes d_out.
// ---------------------------------------------------------------------------
extern "C" void kernel_launch(void* const* d_in, const int* in_sizes, int n_in,
                              void* d_out, int out_size, void* d_ws, size_t ws_size,
                              hipStream_t stream)
{
    const float* x  = (const float*)d_in[0];
    const float* Wq = (const float*)d_in[1];
    const float* bq = (const float*)d_in[2];
    const float* Wk = (const float*)d_in[3];
    const float* bk = (const float*)d_in[4];
    const float* Wv = (const float*)d_in[5];
    const float* bv = (const float*)d_in[6];
    const float* Wo = (const float*)d_in[7];
    const float* bo = (const float*)d_in[8];
    float* out = (float*)d_out;

    const size_t plane = (size_t)HIDDEN * M_TOTAL;   // 16.78M elements
    ushort* qkvt = (ushort*)d_ws;                    // fp16 [3][1024][16384]
    ushort* qt16 = qkvt;
    ushort* kt16 = qkvt + plane;
    ushort* vt16 = qkvt + 2 * plane;
    float*  ot   = (float*)((char*)d_ws + 3 * plane * 2);   // fp32 [1024][16384]
    ushort* woh  = (ushort*)((char*)d_ws + 3 * plane * 2 + plane * 4);  // fp16 [1024][1024]

    // post-fft stash aliases dead qkvt fp16 region
    ushort* oth = qkvt;                              // [16384][1024] fp16

    // fp16 operand stash in d_out (dead before gemm_out writes d_out)
    ushort* xh  = (ushort*)d_out;                    // [16384][1024]
    ushort* wh  = xh + plane;                        // stacked [3072][1024]

    // pre-passes: x -> fp16; all W -> fp16 in ONE launch
    cvt16_kernel<<<(unsigned)(plane / 2048), 256, 0, stream>>>(x, xh);
    cvtW_kernel<<<dim3((unsigned)(WSZ / 2048), 4), 256, 0, stream>>>(
        Wq, Wk, Wv, Wo, wh, woh);

    // QKV projections (full batch, 768 blocks = 3x256) -> fp16 planes
    gemm_qkv_mfma8<<<dim3(M_TOTAL / 256, 12), 1024, 0, stream>>>(
        xh, wh, bq, bk, bv, qkvt);

    // FFT attention (fp16 in, fp32 out)
    fft_attn_kernel<<<dim3(HIDDEN * BATCH), 256, 0, stream>>>(
        qt16, kt16, vt16, ot);

    // transpose ot -> fp16 [m][k] into dead qkvt region
    transpose_cvt_kernel<<<dim3(M_TOTAL / 64, HIDDEN / 64), 256, 0, stream>>>(
        ot, oth);

    // output projection (256 blocks, overwrites d_out)
    gemm_out_mfma8<<<dim3(M_TOTAL / 256, HIDDEN / 256), 1024, 0, stream>>>(
        oth, woh, bo, out);
}

// Round 22
// 249.243 us; speedup vs baseline: 1.6045x; 1.1079x over previous
//
#include <hip/hip_runtime.h>
#include <hip/hip_bf16.h>
#include <math.h>

#define HIDDEN   1024
#define HEADS    16
#define HEAD_DIM 64
#define BATCH    4
#define SEQ      4096
#define M_TOTAL  (BATCH * SEQ)          // 16384
#define FFT_N    4096
#define WSZ      ((size_t)HIDDEN * HIDDEN)
#define PI2      6.28318530717958647692f

typedef _Float16 f16x8 __attribute__((ext_vector_type(8)));   // 8 fp16 = 4 VGPR (MFMA A/B frag)
typedef float    f32x4 __attribute__((ext_vector_type(4)));   // MFMA C/D frag

#if defined(__has_builtin)
#if __has_builtin(__builtin_amdgcn_global_load_lds)
#define HAVE_GLL 1
#else
#define HAVE_GLL 0
#endif
#else
#define HAVE_GLL 0
#endif

#if HAVE_GLL
// async global->LDS, 16B/lane. dest = wave-uniform base + lane*16 (linear in slot).
__device__ __forceinline__ void gload16(const void* g, void* l) {
    __builtin_amdgcn_global_load_lds(
        (const __attribute__((address_space(1))) unsigned int*)g,
        (__attribute__((address_space(3))) unsigned int*)l,
        16, 0, 0);
}
#endif

__device__ __forceinline__ void cvt8_f16(float4 v0, float4 v1,
                                         ushort* __restrict__ d) {
    const float vv[8] = {v0.x, v0.y, v0.z, v0.w, v1.x, v1.y, v1.z, v1.w};
    f16x8 hv;
    #pragma unroll
    for (int e = 0; e < 8; ++e) hv[e] = (_Float16)vv[e];
    *(f16x8*)d = hv;
}

// ---------------------------------------------------------------------------
// Pre-pass kernels (r20-validated): x -> fp16; all four W -> fp16, one launch.
// ---------------------------------------------------------------------------
__global__ __launch_bounds__(256) void cvt16_kernel(
    const float* __restrict__ src, ushort* __restrict__ h)
{
    const size_t i = ((size_t)blockIdx.x * 256 + threadIdx.x) * 8;
    float4 v0 = *(const float4*)(src + i);
    float4 v1 = *(const float4*)(src + i + 4);
    cvt8_f16(v0, v1, h + i);
}

__global__ __launch_bounds__(256) void cvtW_kernel(
    const float* __restrict__ Wq, const float* __restrict__ Wk,
    const float* __restrict__ Wv, const float* __restrict__ Wo,
    ushort* __restrict__ wh, ushort* __restrict__ woh)
{
    const int p = blockIdx.y;                 // 0=q 1=k 2=v 3=o
    const size_t i = ((size_t)blockIdx.x * 256 + threadIdx.x) * 8;
    const float* __restrict__ src = (p == 0) ? Wq : (p == 1 ? Wk : (p == 2 ? Wv : Wo));
    ushort* __restrict__ dst = (p < 3) ? (wh + (size_t)p * WSZ) : woh;
    float4 v0 = *(const float4*)(src + i);
    float4 v1 = *(const float4*)(src + i + 4);
    cvt8_f16(v0, v1, dst + i);
}

// ---------------------------------------------------------------------------
// QKV GEMM (r20-VALIDATED, byte-identical): fp16 1-product, gload16 staging,
// 3-slot counted vmcnt(2).
// ---------------------------------------------------------------------------
__global__ __launch_bounds__(1024, 1) void gemm_qkv_mfma8(
    const ushort* __restrict__ xh, const ushort* __restrict__ wh,
    const float* __restrict__ bq, const float* __restrict__ bk,
    const float* __restrict__ bv,
    ushort* __restrict__ qkvt)
{
    __shared__ ushort Ah[3][8192];   // W tile [256n][32k] fp16
    __shared__ ushort Bh[3][8192];   // x tile [256m][32k] fp16 (96 KiB total)

    const int tid  = threadIdx.x;
    const int lane = tid & 63;
    const int wid  = tid >> 6;
    const int wr   = wid >> 2;
    const int wc   = wid & 3;
    const int m0   = blockIdx.x * 256;
    const int ng0  = blockIdx.y * 256;
    const int p    = ng0 >> 10;
    const int n0p  = ng0 & 1023;

    const float* __restrict__ bias = (p == 0) ? bq : (p == 1 ? bk : bv);
    ushort* __restrict__ ct = qkvt + (size_t)p * HIDDEN * M_TOTAL;

    const int row = tid >> 2;
    const int chS = (tid & 3) ^ ((row >> 1) & 3);

    const int fr = lane & 15;
    const int fc = lane >> 4;
    const int cc = (fc ^ ((fr >> 1) & 3)) * 8;

    f32x4 acc[4][4];
    #pragma unroll
    for (int rf = 0; rf < 4; ++rf)
        #pragma unroll
        for (int cf = 0; cf < 4; ++cf)
            acc[rf][cf] = (f32x4){0.f, 0.f, 0.f, 0.f};

#if HAVE_GLL
    #define QKV_STAGE(K0, SLOT) {                                                  \
        const size_t gw = (size_t)(ng0 + row) * HIDDEN + (K0) + (size_t)chS * 8;   \
        const size_t gx = (size_t)(m0 + row) * HIDDEN + (K0) + (size_t)chS * 8;    \
        gload16(wh + gw, &Ah[SLOT][(size_t)tid * 8]);                              \
        gload16(xh + gx, &Bh[SLOT][(size_t)tid * 8]);                              \
    }
#else
    #define QKV_STAGE(K0, SLOT) {                                                  \
        const size_t gw = (size_t)(ng0 + row) * HIDDEN + (K0) + (size_t)chS * 8;   \
        const size_t gx = (size_t)(m0 + row) * HIDDEN + (K0) + (size_t)chS * 8;    \
        *(f16x8*)&Ah[SLOT][(size_t)tid * 8] = *(const f16x8*)(wh + gw);            \
        *(f16x8*)&Bh[SLOT][(size_t)tid * 8] = *(const f16x8*)(xh + gx);            \
    }
#endif

    QKV_STAGE(0, 0);
    QKV_STAGE(32, 1);

    for (int ks = 0; ks < 32; ++ks) {
        const int slot = ks % 3;
#if HAVE_GLL
        if (ks == 31) { asm volatile("s_waitcnt vmcnt(0)" ::: "memory"); }
        else          { asm volatile("s_waitcnt vmcnt(2)" ::: "memory"); }
        __builtin_amdgcn_s_barrier();
        asm volatile("" ::: "memory");
#else
        __syncthreads();
#endif
        {
            const ushort* pAh = Ah[slot];
            const ushort* pBh = Bh[slot];
            f16x8 a_h[4], b_h[4];
            #pragma unroll
            for (int rf = 0; rf < 4; ++rf) {
                const int R = wr * 64 + rf * 16 + fr;
                a_h[rf] = *(const f16x8*)(pAh + R * 32 + cc);
            }
            #pragma unroll
            for (int cf = 0; cf < 4; ++cf) {
                const int R = wc * 64 + cf * 16 + fr;
                b_h[cf] = *(const f16x8*)(pBh + R * 32 + cc);
            }
            #pragma unroll
            for (int rf = 0; rf < 4; ++rf)
                #pragma unroll
                for (int cf = 0; cf < 4; ++cf)
                    acc[rf][cf] = __builtin_amdgcn_mfma_f32_16x16x32_f16(a_h[rf], b_h[cf], acc[rf][cf], 0, 0, 0);
        }
        if (ks + 2 < 32) { QKV_STAGE((ks + 2) * 32, (ks + 2) % 3); }
#if !HAVE_GLL
        __syncthreads();
#endif
    }
    #undef QKV_STAGE

    const int rq = lane >> 4;
    #pragma unroll
    for (int rf = 0; rf < 4; ++rf) {
        #pragma unroll
        for (int r = 0; r < 4; ++r) {
            const int nl = wr * 64 + rf * 16 + rq * 4 + r;
            const float bv = bias[n0p + nl];
            ushort* dst = ct + (size_t)(n0p + nl) * M_TOTAL + m0 + wc * 64;
            #pragma unroll
            for (int cf = 0; cf < 4; ++cf) {
                union { _Float16 f; ushort u; } cvt;
                cvt.f = (_Float16)(acc[rf][cf][r] + bv);
                dst[cf * 16 + fr] = cvt.u;
            }
        }
    }
}

// ---------------------------------------------------------------------------
// Radix-16 FFT, paired sequences (r21 structure, pointwise CONJ BUG FIXED):
// The radix-16 inverse stages (dft16<+1>, positive twiddles) are a TRUE
// inverse DFT; the r5-r20 validated pointwise stores F DIRECTLY (no conj).
// r21 wrongly stored conj(F) (a relic of the r3/r4 radix-2 kernel), which
// time-reverses both packed outputs -> absmax 3824. Fix: H = F1 + i*F2.
// ---------------------------------------------------------------------------
__device__ __forceinline__ float2 cmul(float2 a, float2 b) {
    return {a.x*b.x - a.y*b.y, a.x*b.y + a.y*b.x};
}

__device__ __forceinline__ int phys(int p) { return p ^ ((p >> 4) & 15); }

__device__ __forceinline__ unsigned pk16(float2 v) {
    union { _Float16 f[2]; unsigned u; } c;
    c.f[0] = (_Float16)v.x; c.f[1] = (_Float16)v.y;
    return c.u;
}
__device__ __forceinline__ float2 upk16(unsigned u) {
    union { unsigned uu; _Float16 f[2]; } c; c.uu = u;
    return (float2){(float)c.f[0], (float)c.f[1]};
}

template<int DIR>
__device__ __forceinline__ void dft16(const float2* x, float2* X) {
    float2 t[16];
    #pragma unroll
    for (int n0 = 0; n0 < 4; ++n0) {
        float2 a = x[n0], b = x[n0+4], c = x[n0+8], d = x[n0+12];
        float2 s0 = {a.x+c.x, a.y+c.y}, s1 = {a.x-c.x, a.y-c.y};
        float2 s2 = {b.x+d.x, b.y+d.y}, s3 = {b.x-d.x, b.y-d.y};
        t[n0*4+0] = {s0.x+s2.x, s0.y+s2.y};
        t[n0*4+2] = {s0.x-s2.x, s0.y-s2.y};
        if (DIR < 0) {
            t[n0*4+1] = {s1.x+s3.y, s1.y-s3.x};
            t[n0*4+3] = {s1.x-s3.y, s1.y+s3.x};
        } else {
            t[n0*4+1] = {s1.x-s3.y, s1.y+s3.x};
            t[n0*4+3] = {s1.x+s3.y, s1.y-s3.x};
        }
    }
    const float C1 = 0.92387953251128674f;
    const float S1_ = 0.38268343236508978f;
    const float R2 = 0.70710678118654752f;
    #define TW(idx, cc_, ss_) t[idx] = cmul(t[idx], (float2){cc_, DIR*(ss_)})
    TW(1*4+1, C1, S1_);   TW(1*4+2, R2, R2);    TW(1*4+3, S1_, C1);
    TW(2*4+1, R2, R2);    TW(2*4+2, 0.f, 1.f);  TW(2*4+3, -R2, R2);
    TW(3*4+1, S1_, C1);   TW(3*4+2, -R2, R2);   TW(3*4+3, -C1, -S1_);
    #undef TW
    #pragma unroll
    for (int k0 = 0; k0 < 4; ++k0) {
        float2 a = t[0+k0], b = t[4+k0], c = t[8+k0], d = t[12+k0];
        float2 s0 = {a.x+c.x, a.y+c.y}, s1 = {a.x-c.x, a.y-c.y};
        float2 s2 = {b.x+d.x, b.y+d.y}, s3 = {b.x-d.x, b.y-d.y};
        X[k0+0]  = {s0.x+s2.x, s0.y+s2.y};
        X[k0+8]  = {s0.x-s2.x, s0.y-s2.y};
        if (DIR < 0) {
            X[k0+4]  = {s1.x+s3.y, s1.y-s3.x};
            X[k0+12] = {s1.x-s3.y, s1.y+s3.x};
        } else {
            X[k0+4]  = {s1.x-s3.y, s1.y+s3.x};
            X[k0+12] = {s1.x+s3.y, s1.y-s3.x};
        }
    }
}

__device__ __forceinline__ void twiddle_apply(float2* y, float ang) {
    float s, c;
    __sincosf(ang, &s, &c);
    const float2 base = {c, s};
    float2 w = base;
    #pragma unroll
    for (int u = 1; u < 16; ++u) {
        y[u] = cmul(y[u], w);
        w = cmul(w, base);
    }
}

__global__ __launch_bounds__(256) void fft_attn_kernel2(
    const ushort* __restrict__ qt, const ushort* __restrict__ kt,
    const ushort* __restrict__ vt, ushort* __restrict__ ot16)
{
    __shared__ unsigned zA[2][FFT_N];   // Z1,Z2 spectra packed fp16 (32 KiB)
    __shared__ float2 bufB[FFT_N];      // V12 / H / inverse ws fp32 (32 KiB)

    const int tid = threadIdx.x;
    const int bid = blockIdx.x;          // [0, 2048)
    const int n   = bid >> 1;
    const int bp  = bid & 1;

    const size_t off0 = (size_t)n * M_TOTAL + (size_t)(2 * bp) * SEQ;
    const size_t off1 = off0 + SEQ;
    const _Float16* q0 = (const _Float16*)qt + off0;
    const _Float16* k0 = (const _Float16*)kt + off0;
    const _Float16* q1 = (const _Float16*)qt + off1;
    const _Float16* k1 = (const _Float16*)kt + off1;
    const _Float16* v0 = (const _Float16*)vt + off0;
    const _Float16* v1 = (const _Float16*)vt + off1;
    _Float16* o0 = (_Float16*)ot16 + off0;
    _Float16* o1 = (_Float16*)ot16 + off1;

    // ---- forward stage 1 (stride 256) from global
    {
        const float ang = -PI2 * (float)tid / 4096.f;
        {   // Z1 = q0 + i k0
            float2 x[16], y[16];
            #pragma unroll
            for (int r = 0; r < 16; ++r)
                x[r] = { (float)q0[tid + 256*r], (float)k0[tid + 256*r] };
            dft16<-1>(x, y);
            twiddle_apply(y, ang);
            #pragma unroll
            for (int u = 0; u < 16; ++u) zA[0][phys(tid + 256*u)] = pk16(y[u]);
        }
        {   // Z2 = q1 + i k1
            float2 x[16], y[16];
            #pragma unroll
            for (int r = 0; r < 16; ++r)
                x[r] = { (float)q1[tid + 256*r], (float)k1[tid + 256*r] };
            dft16<-1>(x, y);
            twiddle_apply(y, ang);
            #pragma unroll
            for (int u = 0; u < 16; ++u) zA[1][phys(tid + 256*u)] = pk16(y[u]);
        }
        {   // V12 = v0 + i v1
            float2 x[16], y[16];
            #pragma unroll
            for (int r = 0; r < 16; ++r)
                x[r] = { (float)v0[tid + 256*r], (float)v1[tid + 256*r] };
            dft16<-1>(x, y);
            twiddle_apply(y, ang);
            #pragma unroll
            for (int u = 0; u < 16; ++u) bufB[phys(tid + 256*u)] = y[u];
        }
    }
    __syncthreads();
    // ---- forward stage 2 (stride 16)
    {
        const int blk = tid >> 4, a = tid & 15;
        const int base = 256*blk + a;
        const float ang = -PI2 * (float)a / 256.f;
        #pragma unroll
        for (int d = 0; d < 2; ++d) {
            float2 x[16], y[16];
            #pragma unroll
            for (int c = 0; c < 16; ++c) x[c] = upk16(zA[d][phys(base + 16*c)]);
            dft16<-1>(x, y);
            twiddle_apply(y, ang);
            #pragma unroll
            for (int c = 0; c < 16; ++c) zA[d][phys(base + 16*c)] = pk16(y[c]);
        }
        {
            float2 x[16], y[16];
            #pragma unroll
            for (int c = 0; c < 16; ++c) x[c] = bufB[phys(base + 16*c)];
            dft16<-1>(x, y);
            twiddle_apply(y, ang);
            #pragma unroll
            for (int c = 0; c < 16; ++c) bufB[phys(base + 16*c)] = y[c];
        }
    }
    __syncthreads();
    // ---- forward stage 3 (contiguous 16)
    {
        const int base = 256*(tid >> 4) + 16*(tid & 15);
        #pragma unroll
        for (int d = 0; d < 2; ++d) {
            float2 x[16], y[16];
            #pragma unroll
            for (int e = 0; e < 16; ++e) x[e] = upk16(zA[d][phys(base + e)]);
            dft16<-1>(x, y);
            #pragma unroll
            for (int e = 0; e < 16; ++e) zA[d][phys(base + e)] = pk16(y[e]);
        }
        {
            float2 x[16], y[16];
            #pragma unroll
            for (int e = 0; e < 16; ++e) x[e] = bufB[phys(base + e)];
            dft16<-1>(x, y);
            #pragma unroll
            for (int e = 0; e < 16; ++e) bufB[phys(base + e)] = y[e];
        }
    }
    __syncthreads();
    // ---- pointwise (paired): H = F1 + i*F2 (NO conj -- the fix), regs then store
    float2 H[16];
    #pragma unroll
    for (int it = 0; it < 16; ++it) {
        const int p  = tid + it * 256;
        const int j  = ((p & 15) << 8) | (p & 0xF0) | (p >> 8);
        const int jn = (FFT_N - j) & (FFT_N - 1);
        const int pn = ((jn & 15) << 8) | (jn & 0xF0) | (jn >> 8);
        const float2 Vj = bufB[phys(p)];
        const float2 Vn = bufB[phys(pn)];
        const float2 V1 = { 0.5f*(Vj.x + Vn.x),  0.5f*(Vj.y - Vn.y) };
        const float2 V2 = { 0.5f*(Vj.y + Vn.y), -0.5f*(Vj.x - Vn.x) };
        float2 F1, F2;
        {
            const float2 Zj = upk16(zA[0][phys(p)]);
            const float2 Zn = upk16(zA[0][phys(pn)]);
            const float2 Q = { 0.5f*(Zj.x + Zn.x),  0.5f*(Zj.y - Zn.y) };
            const float2 K = { 0.5f*(Zj.y + Zn.y), -0.5f*(Zj.x - Zn.x) };
            const float2 G = { Q.x*K.x + Q.y*K.y, Q.y*K.x - Q.x*K.y };
            F1 = { G.x*V1.x - G.y*V1.y, G.x*V1.y + G.y*V1.x };
        }
        {
            const float2 Zj = upk16(zA[1][phys(p)]);
            const float2 Zn = upk16(zA[1][phys(pn)]);
            const float2 Q = { 0.5f*(Zj.x + Zn.x),  0.5f*(Zj.y - Zn.y) };
            const float2 K = { 0.5f*(Zj.y + Zn.y), -0.5f*(Zj.x - Zn.x) };
            const float2 G = { Q.x*K.x + Q.y*K.y, Q.y*K.x - Q.x*K.y };
            F2 = { G.x*V2.x - G.y*V2.y, G.x*V2.y + G.y*V2.x };
        }
        H[it] = { F1.x - F2.y, F1.y + F2.x };   // F1 + i*F2
    }
    __syncthreads();          // all reads of bufB complete before overwrite
    #pragma unroll
    for (int it = 0; it < 16; ++it)
        bufB[phys(tid + it * 256)] = H[it];
    __syncthreads();
    // ---- inverse stage A (contiguous 16)
    {
        const int base = 256*(tid >> 4) + 16*(tid & 15);
        float2 x[16], y[16];
        #pragma unroll
        for (int d = 0; d < 16; ++d) x[d] = bufB[phys(base + d)];
        dft16<1>(x, y);
        #pragma unroll
        for (int p0 = 0; p0 < 16; ++p0) bufB[phys(base + p0)] = y[p0];
    }
    __syncthreads();
    // ---- inverse stage B (stride 16), input twiddle
    {
        const int blk = tid >> 4, p0 = tid & 15;
        const int base = 256*blk + p0;
        float2 x[16], y[16];
        #pragma unroll
        for (int c = 0; c < 16; ++c) x[c] = bufB[phys(base + 16*c)];
        twiddle_apply(x, PI2 * (float)p0 / 256.f);
        dft16<1>(x, y);
        #pragma unroll
        for (int p1 = 0; p1 < 16; ++p1) bufB[phys(base + 16*p1)] = y[p1];
    }
    __syncthreads();
    // ---- inverse stage C (stride 256), twiddle, fp16 dual store
    {
        const int qq = tid;
        float2 x[16], y[16];
        #pragma unroll
        for (int t = 0; t < 16; ++t) x[t] = bufB[phys(qq + 256*t)];
        twiddle_apply(x, PI2 * (float)qq / 4096.f);
        dft16<1>(x, y);
        const float scale = 0.125f / 4096.f;   // 1/sqrt(64) * 1/N
        #pragma unroll
        for (int p2 = 0; p2 < 16; ++p2) {
            o0[qq + 256*p2] = (_Float16)(y[p2].x * scale);
            o1[qq + 256*p2] = (_Float16)(y[p2].y * scale);
        }
    }
}

// ---------------------------------------------------------------------------
// Transpose (fp16 in, fp16 out): ot16 [n][m] -> oth [m][k=n]
// ---------------------------------------------------------------------------
__global__ __launch_bounds__(256) void transpose_cvt_kernel(
    const ushort* __restrict__ ot, ushort* __restrict__ oth)
{
    __shared__ float tile[64][65];
    const int tid = threadIdx.x;
    const int m0  = blockIdx.x * 64;
    const int n0  = blockIdx.y * 64;
    const int r   = tid >> 4;
    const int c   = tid & 15;

    #pragma unroll
    for (int rr = 0; rr < 4; ++rr) {
        const int nl = r + rr * 16;
        ushort4 v = *(const ushort4*)(ot + (size_t)(n0 + nl) * M_TOTAL + m0 + c * 4);
        union { ushort u; _Float16 f; } cv;
        cv.u = v.x; tile[nl][c * 4 + 0] = (float)cv.f;
        cv.u = v.y; tile[nl][c * 4 + 1] = (float)cv.f;
        cv.u = v.z; tile[nl][c * 4 + 2] = (float)cv.f;
        cv.u = v.w; tile[nl][c * 4 + 3] = (float)cv.f;
    }
    __syncthreads();
    #pragma unroll
    for (int rr = 0; rr < 4; ++rr) {
        const int ml = r + rr * 16;
        ushort4 hh;
        union { _Float16 f; ushort u; } cv;
        cv.f = (_Float16)tile[c * 4 + 0][ml]; hh.x = cv.u;
        cv.f = (_Float16)tile[c * 4 + 1][ml]; hh.y = cv.u;
        cv.f = (_Float16)tile[c * 4 + 2][ml]; hh.z = cv.u;
        cv.f = (_Float16)tile[c * 4 + 3][ml]; hh.w = cv.u;
        *(ushort4*)(oth + (size_t)(m0 + ml) * HIDDEN + n0 + c * 4) = hh;
    }
}

// ---------------------------------------------------------------------------
// Output GEMM (r20-VALIDATED, byte-identical): fp16 1-product.
// ---------------------------------------------------------------------------
__global__ __launch_bounds__(1024, 1) void gemm_out_mfma8(
    const ushort* __restrict__ oth, const ushort* __restrict__ woh,
    const float* __restrict__ bo, float* __restrict__ out)
{
    __shared__ ushort Ah[3][8192];
    __shared__ ushort Bh[3][8192];

    const int tid  = threadIdx.x;
    const int lane = tid & 63;
    const int wid  = tid >> 6;
    const int wr   = wid >> 2;
    const int wc   = wid & 3;
    const int m0   = blockIdx.x * 256;
    const int n0   = blockIdx.y * 256;

    const int row = tid >> 2;
    const int chS = (tid & 3) ^ ((row >> 1) & 3);

    const int fr = lane & 15;
    const int fc = lane >> 4;
    const int cc = (fc ^ ((fr >> 1) & 3)) * 8;

    f32x4 acc[4][4];
    #pragma unroll
    for (int rf = 0; rf < 4; ++rf)
        #pragma unroll
        for (int cf = 0; cf < 4; ++cf)
            acc[rf][cf] = (f32x4){0.f, 0.f, 0.f, 0.f};

#if HAVE_GLL
    #define OUT_STAGE(K0, SLOT) {                                                  \
        const size_t ga = (size_t)(m0 + row) * HIDDEN + (K0) + (size_t)chS * 8;    \
        const size_t gb = (size_t)(n0 + row) * HIDDEN + (K0) + (size_t)chS * 8;    \
        gload16(oth + ga, &Ah[SLOT][(size_t)tid * 8]);                             \
        gload16(woh + gb, &Bh[SLOT][(size_t)tid * 8]);                             \
    }
#else
    #define OUT_STAGE(K0, SLOT) {                                                  \
        const size_t ga = (size_t)(m0 + row) * HIDDEN + (K0) + (size_t)chS * 8;    \
        const size_t gb = (size_t)(n0 + row) * HIDDEN + (K0) + (size_t)chS * 8;    \
        *(f16x8*)&Ah[SLOT][(size_t)tid * 8] = *(const f16x8*)(oth + ga);           \
        *(f16x8*)&Bh[SLOT][(size_t)tid * 8] = *(const f16x8*)(woh + gb);           \
    }
#endif

    OUT_STAGE(0, 0);
    OUT_STAGE(32, 1);

    for (int ks = 0; ks < 32; ++ks) {
        const int slot = ks % 3;
#if HAVE_GLL
        if (ks == 31) { asm volatile("s_waitcnt vmcnt(0)" ::: "memory"); }
        else          { asm volatile("s_waitcnt vmcnt(2)" ::: "memory"); }
        __builtin_amdgcn_s_barrier();
        asm volatile("" ::: "memory");
#else
        __syncthreads();
#endif
        {
            const ushort* pAh = Ah[slot];
            const ushort* pBh = Bh[slot];
            f16x8 a_h[4], b_h[4];
            #pragma unroll
            for (int rf = 0; rf < 4; ++rf) {
                const int R = wr * 64 + rf * 16 + fr;
                a_h[rf] = *(const f16x8*)(pAh + R * 32 + cc);
            }
            #pragma unroll
            for (int cf = 0; cf < 4; ++cf) {
                const int R = wc * 64 + cf * 16 + fr;
                b_h[cf] = *(const f16x8*)(pBh + R * 32 + cc);
            }
            #pragma unroll
            for (int rf = 0; rf < 4; ++rf)
                #pragma unroll
                for (int cf = 0; cf < 4; ++cf)
                    acc[rf][cf] = __builtin_amdgcn_mfma_f32_16x16x32_f16(a_h[rf], b_h[cf], acc[rf][cf], 0, 0, 0);
        }
        if (ks + 2 < 32) { OUT_STAGE((ks + 2) * 32, (ks + 2) % 3); }
#if !HAVE_GLL
        __syncthreads();
#endif
    }
    #undef OUT_STAGE

    const int rq = lane >> 4;
    float bo_v[4];
    #pragma unroll
    for (int cf = 0; cf < 4; ++cf) bo_v[cf] = bo[n0 + wc * 64 + cf * 16 + fr];
    #pragma unroll
    for (int rf = 0; rf < 4; ++rf) {
        #pragma unroll
        for (int r = 0; r < 4; ++r) {
            const int ml = wr * 64 + rf * 16 + rq * 4 + r;
            float* dst = out + (size_t)(m0 + ml) * HIDDEN + n0 + wc * 64;
            #pragma unroll
            for (int cf = 0; cf < 4; ++cf)
                dst[cf * 16 + fr] = acc[rf][cf][r] + bo_v[cf];
        }
    }
}

// ---------------------------------------------------------------------------
// Buffers (ws = proven 201.3 MB; peak use 136.3 MB):
//   ws[0..100.66M):        qkvt fp16 [3][1024][16384]
//   ws[100.66..134.2M):    ot16 fp16 [1024][16384]
//   ws[134.2..136.3M):     woh fp16 [1024][1024]
//   After fft: oth (33.5 MB) aliases the dead qkvt region.
//   d_out stash: xh 33.55 + wh 6.29 = 39.8 MB < 67.1; dead before gemm_out.
// ---------------------------------------------------------------------------
extern "C" void kernel_launch(void* const* d_in, const int* in_sizes, int n_in,
                              void* d_out, int out_size, void* d_ws, size_t ws_size,
                              hipStream_t stream)
{
    const float* x  = (const float*)d_in[0];
    const float* Wq = (const float*)d_in[1];
    const float* bq = (const float*)d_in[2];
    const float* Wk = (const float*)d_in[3];
    const float* bk = (const float*)d_in[4];
    const float* Wv = (const float*)d_in[5];
    const float* bv = (const float*)d_in[6];
    const float* Wo = (const float*)d_in[7];
    const float* bo = (const float*)d_in[8];
    float* out = (float*)d_out;

    const size_t plane = (size_t)HIDDEN * M_TOTAL;   // 16.78M elements
    ushort* qkvt = (ushort*)d_ws;                    // fp16 [3][1024][16384]
    ushort* qt16 = qkvt;
    ushort* kt16 = qkvt + plane;
    ushort* vt16 = qkvt + 2 * plane;
    ushort* ot16 = qkvt + 3 * plane;                 // fp16 [1024][16384]
    ushort* woh  = ot16 + plane;                     // fp16 [1024][1024]

    // post-fft stash aliases dead qkvt region
    ushort* oth = qkvt;                              // [16384][1024] fp16

    // fp16 operand stash in d_out (dead before gemm_out writes d_out)
    ushort* xh  = (ushort*)d_out;                    // [16384][1024]
    ushort* wh  = xh + plane;                        // stacked [3072][1024]

    // pre-passes
    cvt16_kernel<<<(unsigned)(plane / 2048), 256, 0, stream>>>(x, xh);
    cvtW_kernel<<<dim3((unsigned)(WSZ / 2048), 4), 256, 0, stream>>>(
        Wq, Wk, Wv, Wo, wh, woh);

    // QKV projections
    gemm_qkv_mfma8<<<dim3(M_TOTAL / 256, 12), 1024, 0, stream>>>(
        xh, wh, bq, bk, bv, qkvt);

    // FFT attention: 2 sequences per block, fp16 in/out
    fft_attn_kernel2<<<dim3(HIDDEN * BATCH / 2), 256, 0, stream>>>(
        qt16, kt16, vt16, ot16);

    // transpose ot16 -> oth [m][k]
    transpose_cvt_kernel<<<dim3(M_TOTAL / 64, HIDDEN / 64), 256, 0, stream>>>(
        ot16, oth);

    // output projection
    gemm_out_mfma8<<<dim3(M_TOTAL / 256, HIDDEN / 256), 1024, 0, stream>>>(
        oth, woh, bo, out);
}